// Round 9
// baseline (379.072 us; speedup 1.0000x reference)
//
#include <hip/hip_runtime.h>

typedef __attribute__((ext_vector_type(8))) short bf16x8;
typedef __attribute__((ext_vector_type(4))) float f32x4;
typedef unsigned short u16;
typedef unsigned int u32;

#define B_ 8
#define T_ 512
#define C_ 1024
#define I_ 4096
#define H_ 16
#define Dh_ 64
#define BT (B_*T_)
#define NH (B_*H_)

// ---------------- helpers ----------------
__device__ __forceinline__ float bf2f(u16 u) {
  return __uint_as_float(((u32)u) << 16);
}
__device__ __forceinline__ u16 f2bf(float f) {
  u32 u = __float_as_uint(f);
  u32 r = u + 0x7FFFu + ((u >> 16) & 1u);
  return (u16)(r >> 16);
}
__device__ __forceinline__ float wredMax(float v) {
#pragma unroll
  for (int o = 32; o; o >>= 1) v = fmaxf(v, __shfl_xor(v, o));
  return v;
}
__device__ __forceinline__ float wredSum(float v) {
#pragma unroll
  for (int o = 32; o; o >>= 1) v += __shfl_xor(v, o);
  return v;
}
// Conditional atomic: only RMW if our value beats the currently visible max.
// Stale reads are always <= true max (monotone), so skipping is safe.
__device__ __forceinline__ void condAtomicMax(u32* amax, float bm) {
  u32 b = __float_as_uint(bm);  // bm >= 0 so uint compare == float compare
  if (b > *(volatile u32*)amax) atomicMax(amax, b);
}
// global -> LDS direct copy, 16B per lane; lds dest is wave-uniform base,
// lane l lands at base + l*16 bytes.
__device__ __forceinline__ void gload16(const void* g, void* l) {
  __builtin_amdgcn_global_load_lds((const __attribute__((address_space(1))) void*)g,
                                   (__attribute__((address_space(3))) void*)l, 16, 0, 0);
}

// ---------------- small kernels ----------------
__global__ void k_init(u32* s) { if (threadIdx.x < 16) s[threadIdx.x] = 0u; }

// absmax of 4 independent f32 arrays -> amax[0..3]
__global__ __launch_bounds__(256) void k_absmax4(
    const float* __restrict__ p0, int n0,
    const float* __restrict__ p1, int n1,
    const float* __restrict__ p2, int n2,
    const float* __restrict__ p3, int n3,
    u32* __restrict__ amax) {
  int stride = gridDim.x * blockDim.x;
  int gid = blockIdx.x * blockDim.x + threadIdx.x;
  float m0 = 0.f, m1 = 0.f, m2 = 0.f, m3 = 0.f;
  for (int i = gid; i < n0; i += stride) {
    float4 v = ((const float4*)p0)[i];
    m0 = fmaxf(m0, fmaxf(fmaxf(fabsf(v.x), fabsf(v.y)), fmaxf(fabsf(v.z), fabsf(v.w))));
  }
  for (int i = gid; i < n1; i += stride) {
    float4 v = ((const float4*)p1)[i];
    m1 = fmaxf(m1, fmaxf(fmaxf(fabsf(v.x), fabsf(v.y)), fmaxf(fabsf(v.z), fabsf(v.w))));
  }
  for (int i = gid; i < n2; i += stride) {
    float4 v = ((const float4*)p2)[i];
    m2 = fmaxf(m2, fmaxf(fmaxf(fabsf(v.x), fabsf(v.y)), fmaxf(fabsf(v.z), fabsf(v.w))));
  }
  for (int i = gid; i < n3; i += stride) {
    float4 v = ((const float4*)p3)[i];
    m3 = fmaxf(m3, fmaxf(fmaxf(fabsf(v.x), fabsf(v.y)), fmaxf(fabsf(v.z), fabsf(v.w))));
  }
  m0 = wredMax(m0); m1 = wredMax(m1); m2 = wredMax(m2); m3 = wredMax(m3);
  __shared__ float red[4][4];
  int wid = threadIdx.x >> 6, lane = threadIdx.x & 63;
  if (lane == 0) { red[wid][0] = m0; red[wid][1] = m1; red[wid][2] = m2; red[wid][3] = m3; }
  __syncthreads();
  if (threadIdx.x < 4) {
    int j = threadIdx.x;
    float bm = fmaxf(fmaxf(red[0][j], red[1][j]), fmaxf(red[2][j], red[3][j]));
    condAtomicMax(amax + j, bm);
  }
}

__device__ __forceinline__ float fq1(float v, float s, float inv) {
  return fminf(fmaxf(rintf(v * inv), -127.f), 127.f) * s;
}

// fake-quant 4 independent f32 arrays -> bf16, scales from amax[0..3]
__global__ __launch_bounds__(256) void k_quant4(
    const float* __restrict__ p0, u16* __restrict__ q0, int n0,
    const float* __restrict__ p1, u16* __restrict__ q1, int n1,
    const float* __restrict__ p2, u16* __restrict__ q2, int n2,
    const float* __restrict__ p3, u16* __restrict__ q3, int n3,
    const u32* __restrict__ amax) {
  int stride = gridDim.x * blockDim.x;
  int gid = blockIdx.x * blockDim.x + threadIdx.x;
#define QLOOP(p, q, n, slot)                                                       \
  {                                                                                \
    float s = fmaxf(__uint_as_float(amax[slot]) / 127.0f, 1e-8f);                  \
    float inv = 1.0f / s;                                                          \
    for (int i = gid; i < n; i += stride) {                                        \
      float4 v = ((const float4*)p)[i];                                            \
      ushort4 o;                                                                   \
      o.x = f2bf(fq1(v.x, s, inv));                                                \
      o.y = f2bf(fq1(v.y, s, inv));                                                \
      o.z = f2bf(fq1(v.z, s, inv));                                                \
      o.w = f2bf(fq1(v.w, s, inv));                                                \
      ((ushort4*)q)[i] = o;                                                        \
    }                                                                              \
  }
  QLOOP(p0, q0, n0, 0)
  QLOOP(p1, q1, n1, 1)
  QLOOP(p2, q2, n2, 2)
  QLOOP(p3, q3, n3, 3)
#undef QLOOP
}

// fake-quant bf16 src -> bf16 dst (different buffers)
__global__ __launch_bounds__(256) void k_quant_b(const u16* __restrict__ x, u16* __restrict__ q, int n8,
                                                 const u32* __restrict__ amax) {
  float s = fmaxf(__uint_as_float(*amax) / 127.0f, 1e-8f);
  float inv = 1.0f / s;
  int stride = gridDim.x * blockDim.x;
  for (int i = blockIdx.x * blockDim.x + threadIdx.x; i < n8; i += stride) {
    uint4 d = ((const uint4*)x)[i];
    u16* e = (u16*)&d;
#pragma unroll
    for (int j = 0; j < 8; j++) e[j] = f2bf(fq1(bf2f(e[j]), s, inv));
    ((uint4*)q)[i] = d;
  }
}

// fake-quant bf16 in-place
__global__ __launch_bounds__(256) void k_quant_bf16(u16* __restrict__ x, int n8, const u32* __restrict__ amax) {
  float s = fmaxf(__uint_as_float(*amax) / 127.0f, 1e-8f);
  float inv = 1.0f / s;
  int stride = gridDim.x * blockDim.x;
  for (int i = blockIdx.x * blockDim.x + threadIdx.x; i < n8; i += stride) {
    uint4 d = ((uint4*)x)[i];
    u16* e = (u16*)&d;
#pragma unroll
    for (int j = 0; j < 8; j++) e[j] = f2bf(fq1(bf2f(e[j]), s, inv));
    ((uint4*)x)[i] = d;
  }
}

// LayerNorm row (C=1024) -> bf16 out + global absmax (block-reduced)
__global__ __launch_bounds__(256) void k_ln(const float* __restrict__ x, const float* __restrict__ g,
                                            const float* __restrict__ b, u16* __restrict__ y,
                                            u32* __restrict__ amax) {
  int row = blockIdx.x;
  int t = threadIdx.x;
  float4 v = ((const float4*)(x + (long)row * C_))[t];
  float s1 = v.x + v.y + v.z + v.w;
  float s2 = v.x * v.x + v.y * v.y + v.z * v.z + v.w * v.w;
  s1 = wredSum(s1);
  s2 = wredSum(s2);
  __shared__ float red[8];
  int wid = t >> 6, lane = t & 63;
  if (lane == 0) { red[wid] = s1; red[4 + wid] = s2; }
  __syncthreads();
  s1 = red[0] + red[1] + red[2] + red[3];
  s2 = red[4] + red[5] + red[6] + red[7];
  float mean = s1 * (1.0f / C_);
  float var = s2 * (1.0f / C_) - mean * mean;
  float inv = rsqrtf(var + 1e-5f);
  float4 gv = ((const float4*)g)[t];
  float4 bv = ((const float4*)b)[t];
  float4 o;
  o.x = (v.x - mean) * inv * gv.x + bv.x;
  o.y = (v.y - mean) * inv * gv.y + bv.y;
  o.z = (v.z - mean) * inv * gv.z + bv.z;
  o.w = (v.w - mean) * inv * gv.w + bv.w;
  ushort4 ob;
  ob.x = f2bf(o.x); ob.y = f2bf(o.y); ob.z = f2bf(o.z); ob.w = f2bf(o.w);
  ((ushort4*)(y + (long)row * C_))[t] = ob;
  float m = fmaxf(fmaxf(fabsf(o.x), fabsf(o.y)), fmaxf(fabsf(o.z), fabsf(o.w)));
  m = wredMax(m);
  __syncthreads();  // all threads done reading red[] for the sums
  if (lane == 0) red[wid] = m;
  __syncthreads();
  if (t == 0) {
    float bm = fmaxf(fmaxf(red[0], red[1]), fmaxf(red[2], red[3]));
    condAtomicMax(amax, bm);
  }
}

// softmax over rows of 512, bf16 in-place; one wave per row
__global__ __launch_bounds__(256) void k_softmax(u16* __restrict__ S) {
  int r = blockIdx.x * 4 + (threadIdx.x >> 6);
  int lane = threadIdx.x & 63;
  u16* row = S + (long)r * T_ + lane * 8;
  uint4 d = *(const uint4*)row;
  u16* e = (u16*)&d;
  float v[8];
  float mx = -3.0e38f;
#pragma unroll
  for (int j = 0; j < 8; j++) { v[j] = bf2f(e[j]); mx = fmaxf(mx, v[j]); }
  mx = wredMax(mx);
  float sum = 0.f;
#pragma unroll
  for (int j = 0; j < 8; j++) { v[j] = expf(v[j] - mx); sum += v[j]; }
  sum = wredSum(sum);
  float inv = 1.0f / sum;
#pragma unroll
  for (int j = 0; j < 8; j++) e[j] = f2bf(v[j] * inv);
  *(uint4*)row = d;
}

// ---------------- unified MFMA GEMM ----------------
// C[M,N] = A[M,K] * B^T + epilogue.  B normally [N,K] row-major; EPI==5: B is [K,N].
// BK=64 (128B rows) with XOR slot-swizzle: element (r, slot) stored at
// phys slot = slot ^ (r&7).  Staging via global_load_lds with PRE-SWIZZLED
// per-lane global source (linear LDS dest); ds_read uses the same XOR.
// DOUBLE-BUFFERED pipeline (T3-minimum): per K-step {STAGE next buf; ds_read+
// MFMA cur buf; s_waitcnt vmcnt(0) lgkmcnt(0); s_barrier} -- one barrier per
// K-step, staging latency hides under compute.
// SWZ: bijective XCD chunk-swizzle of (bx,by) for L2 A-panel locality.
// EPI: 0 = +bias -> bf16
//      1 = +bias +resid(f32) -> f32
//      2 = +bias, gelu(tanh-form), absmax -> bf16
//      3 = +bias +resid(f32) -> f32 (final output)
//      4 = *scale + mask-ext -> bf16 (scores)
//      5 = absmax -> bf16 (PV; B in [K,N])
template <int BM, int BN, int EPI, bool SWZ>
__global__ __launch_bounds__(256) void k_gemm(
    const u16* __restrict__ A, int lda, long sAb, long sAh,
    const u16* __restrict__ Bm, int ldb, long sBb, long sBh,
    const float* __restrict__ bias,
    void* __restrict__ Cp, int ldc, long sCb, long sCh,
    int M, int N, int K, int bH,
    const float* __restrict__ resid,
    u32* __restrict__ amax,
    const float* __restrict__ mask, float scale) {
  constexpr int BK = 64;
  constexpr int MF = (BM / 2) / 16;
  constexpr int NF = (BN / 2) / 16;
  __shared__ u16 As[2][BM * BK];
  __shared__ u16 Bs[2][BN * BK];
  const int tid = threadIdx.x;
  const int wid = tid >> 6, lane = tid & 63;
  const int wr = wid >> 1, wc = wid & 1;
  const int bz = blockIdx.z;
  const int bb = bz / bH, hh = bz % bH;

  int bx = blockIdx.x, by = blockIdx.y;
  if (SWZ) {
    int gx = gridDim.x;
    int nwg = gx * gridDim.y;       // must be % 8 == 0 (all SWZ call sites are)
    int bid = by * gx + bx;
    int cpx = nwg >> 3;
    int swz = (bid & 7) * cpx + (bid >> 3);
    bx = swz % gx;
    by = swz / gx;
  }

  const u16* Ab = A + bb * sAb + hh * sAh + (long)by * BM * lda;
  const u16* Bb;
  if (EPI == 5)
    Bb = Bm + bb * sBb + hh * sBh + bx * BN;  // [K,N]: column offset
  else
    Bb = Bm + bb * sBb + hh * sBh + (long)bx * BN * ldb;

  f32x4 acc[MF][NF];
#pragma unroll
  for (int m = 0; m < MF; m++)
#pragma unroll
    for (int n = 0; n < NF; n++) acc[m][n] = (f32x4){0.f, 0.f, 0.f, 0.f};

  const int lr = lane & 15;
  // pre-swizzled staging source offsets (stripe base is 8-row aligned, so
  // row&7 == lane>>3 independent of stripe)
  const int l8 = lane >> 3;              // row within 8-row stripe
  const int s8 = (lane & 7) ^ l8;        // swizzled slot to fetch
  const long aoff = (long)l8 * lda + (s8 << 3);
  const long boff = (long)l8 * ldb + (s8 << 3);

  // ---- staging (issue only; no waits) ----
  auto stageAB = [&](int buf, int k0) {
#pragma unroll
    for (int i = 0; i < BM / 32; ++i) {
      int R0 = wid * (BM / 4) + i * 8;
      gload16(Ab + (long)R0 * lda + k0 + aoff, &As[buf][R0 * 64]);
    }
    if (EPI == 5) {
      // Bs[n][kk] = Bb[(k0+kk)*ldb + n], swizzled scatter (BN==64)
      int kk = tid >> 2;
      int sp = kk >> 3, k7 = kk & 7;
#pragma unroll
      for (int h = 0; h < 2; ++h) {
        int n0 = ((tid & 3) + h * 4) * 8;
        uint4 t4 = *(const uint4*)(Bb + (long)(k0 + kk) * ldb + n0);
        u16* tv = (u16*)&t4;
#pragma unroll
        for (int j = 0; j < 8; j++)
          Bs[buf][(n0 + j) * 64 + ((sp ^ j) << 3) + k7] = tv[j];
      }
    } else {
#pragma unroll
      for (int i = 0; i < BN / 32; ++i) {
        int R0 = wid * (BN / 4) + i * 8;
        gload16(Bb + (long)R0 * ldb + k0 + boff, &Bs[buf][R0 * 64]);
      }
    }
  };

  // ---- compute one K-tile from buf ----
  auto computeK = [&](int buf) {
#pragma unroll
    for (int kk = 0; kk < 2; ++kk) {
      const int sl = (kk << 2) + (lane >> 4);
      const int sf = (sl ^ (lr & 7)) << 3;
      bf16x8 af[MF], bfr[NF];
#pragma unroll
      for (int m = 0; m < MF; m++)
        af[m] = *(const bf16x8*)&As[buf][(wr * (BM / 2) + m * 16 + lr) * 64 + sf];
#pragma unroll
      for (int n = 0; n < NF; n++)
        bfr[n] = *(const bf16x8*)&Bs[buf][(wc * (BN / 2) + n * 16 + lr) * 64 + sf];
      __builtin_amdgcn_s_setprio(1);
#pragma unroll
      for (int m = 0; m < MF; m++)
#pragma unroll
        for (int n = 0; n < NF; n++)
          acc[m][n] = __builtin_amdgcn_mfma_f32_16x16x32_bf16(af[m], bfr[n], acc[m][n], 0, 0, 0);
      __builtin_amdgcn_s_setprio(0);
    }
  };

  const int nt = K / BK;
  // prologue
  stageAB(0, 0);
  asm volatile("s_waitcnt vmcnt(0) lgkmcnt(0)" ::: "memory");
  __builtin_amdgcn_s_barrier();
  int cur = 0;
  for (int t = 0; t < nt - 1; ++t) {
    stageAB(cur ^ 1, (t + 1) * BK);   // issue next-tile loads (overlap compute)
    computeK(cur);
    asm volatile("s_waitcnt vmcnt(0) lgkmcnt(0)" ::: "memory");
    __builtin_amdgcn_s_barrier();     // next tile staged & cur fully consumed
    cur ^= 1;
  }
  computeK(cur);                      // last tile, no prefetch

  const int rowBase = by * BM + wr * (BM / 2);
  const int colBase = bx * BN + wc * (BN / 2);
  const long cb = bb * sCb + hh * sCh;
  float lmax = 0.f;
#pragma unroll
  for (int m = 0; m < MF; m++) {
    int row0 = rowBase + m * 16 + (lane >> 4) * 4;
#pragma unroll
    for (int n = 0; n < NF; n++) {
      int col = colBase + n * 16 + lr;
      float bs = 0.f, ext = 0.f;
      if (EPI == 0 || EPI == 1 || EPI == 2 || EPI == 3) bs = bias[col];
      if (EPI == 4) ext = (1.0f - mask[bb * T_ + col]) * -10000.0f;
#pragma unroll
      for (int j = 0; j < 4; j++) {
        int row = row0 + j;
        long idx = cb + (long)row * ldc + col;
        float v = acc[m][n][j];
        if (EPI == 0) {
          ((u16*)Cp)[idx] = f2bf(v + bs);
        } else if (EPI == 1) {
          ((float*)Cp)[idx] = v + bs + resid[idx];
        } else if (EPI == 2) {
          v += bs;
          // gelu tanh-form: x * sigmoid(2*(0.79788456*(x+0.044715 x^3)))
          float x2 = v * v;
          float e = __expf(v * fmaf(-0.0713548755f, x2, -1.5957691216f));
          v = v * __builtin_amdgcn_rcpf(1.0f + e);
          lmax = fmaxf(fmaxf(lmax, v), 0.0f - v);  // v_max3
          ((u16*)Cp)[idx] = f2bf(v);
        } else if (EPI == 3) {
          ((float*)Cp)[idx] = v + bs + resid[idx];
        } else if (EPI == 4) {
          ((u16*)Cp)[idx] = f2bf(v * scale + ext);
        } else {
          lmax = fmaxf(fmaxf(lmax, v), 0.0f - v);  // v_max3
          ((u16*)Cp)[idx] = f2bf(v);
        }
      }
    }
  }
  if (EPI == 2 || EPI == 5) {
    __shared__ float redm[4];
    float wm = wredMax(lmax);
    if (lane == 0) redm[wid] = wm;
    __syncthreads();
    if (tid == 0) {
      float bm = fmaxf(fmaxf(redm[0], redm[1]), fmaxf(redm[2], redm[3]));
      condAtomicMax(amax, bm);
    }
  }
}

// ---------------- host ----------------
extern "C" void kernel_launch(void* const* d_in, const int* in_sizes, int n_in,
                              void* d_out, int out_size, void* d_ws, size_t ws_size,
                              hipStream_t stream) {
  const float* hidden = (const float*)d_in[0];
  const float* mask = (const float*)d_in[1];
  const float* ln1g = (const float*)d_in[2];
  const float* ln1b = (const float*)d_in[3];
  const float* ln2g = (const float*)d_in[4];
  const float* ln2b = (const float*)d_in[5];
  const float* w_qkv = (const float*)d_in[6];
  const float* b_qkv = (const float*)d_in[7];
  const float* w_out = (const float*)d_in[8];
  const float* b_out = (const float*)d_in[9];
  const float* w1 = (const float*)d_in[10];
  const float* b1 = (const float*)d_in[11];
  const float* w2 = (const float*)d_in[12];
  const float* b2 = (const float*)d_in[13];

  char* ws = (char*)d_ws;
  u32* sc = (u32*)ws;  // [0]wqkv [1]wout [2]w1 [3]w2 [4]x1 [5]O [6]x2 [7]y1
  u16* wq_qkv = (u16*)(ws + 256);
  u16* wq_out = (u16*)(ws + 6291712);
  u16* wq_w1 = (u16*)(ws + 8388864);
  u16* wq_w2 = (u16*)(ws + 16777472);
  u16* x1 = (u16*)(ws + 25166080);       // LN output, bf16 (also x2)
  u16* xq = (u16*)(ws + 41943296);       // also x2q
  u16* qkv = (u16*)(ws + 50331904);
  u16* S = (u16*)(ws + 75497728);        // scores/P; later y1 (raw+quant)
  u16* O = (u16*)(ws + 142606592);
  float* hbuf = (float*)(ws + 150995200);
  // total ws use: 167,772,416 bytes

  k_init<<<1, 64, 0, stream>>>(sc);

  // weight fake-quant (merged: 2 launches)
  k_absmax4<<<512, 256, 0, stream>>>(
      w_qkv, 3 * C_ * C_ / 4, w_out, C_ * C_ / 4, w1, I_ * C_ / 4, w2, C_ * I_ / 4, sc);
  k_quant4<<<512, 256, 0, stream>>>(
      w_qkv, wq_qkv, 3 * C_ * C_ / 4, w_out, wq_out, C_ * C_ / 4,
      w1, wq_w1, I_ * C_ / 4, w2, wq_w2, C_ * I_ / 4, sc);

  // LN1 (bf16 out) + fq(x)
  k_ln<<<BT, 256, 0, stream>>>(hidden, ln1g, ln1b, x1, sc + 4);
  k_quant_b<<<512, 256, 0, stream>>>(x1, xq, BT * C_ / 8, sc + 4);

  // qkv = xq @ wq_qkv^T + b  -> bf16 [4096,3072]
  k_gemm<128, 128, 0, true><<<dim3(24, 32, 1), 256, 0, stream>>>(
      xq, C_, 0, 0, wq_qkv, C_, 0, 0, b_qkv, qkv, 3 * C_, 0, 0,
      BT, 3 * C_, C_, 1, nullptr, nullptr, nullptr, 0.f);

  // scores = Q K^T * scale + ext -> bf16 [128][512][512]
  k_gemm<128, 128, 4, false><<<dim3(4, 4, NH), 256, 0, stream>>>(
      qkv, 3 * C_, (long)T_ * 3 * C_, Dh_,
      qkv + C_, 3 * C_, (long)T_ * 3 * C_, Dh_,
      nullptr,
      S, T_, (long)H_ * T_ * T_, (long)T_ * T_,
      T_, T_, Dh_, H_, nullptr, nullptr, mask, 0.125f);

  k_softmax<<<NH * T_ / 4, 256, 0, stream>>>(S);

  // O = P @ V  (B in [K,N])  -> bf16 [4096,1024] in (b,t,h*64+d) layout, + absmax
  k_gemm<128, 64, 5, false><<<dim3(1, 4, NH), 256, 0, stream>>>(
      S, T_, (long)H_ * T_ * T_, (long)T_ * T_,
      qkv + 2 * C_, 3 * C_, (long)T_ * 3 * C_, Dh_,
      nullptr,
      O, C_, (long)T_ * C_, (long)Dh_,
      T_, Dh_, T_, H_, nullptr, sc + 5, nullptr, 0.f);

  k_quant_bf16<<<512, 256, 0, stream>>>(O, BT * C_ / 8, sc + 5);

  // h = hidden + Oq @ wq_out^T + b  -> f32
  k_gemm<64, 128, 1, true><<<dim3(8, 64, 1), 256, 0, stream>>>(
      O, C_, 0, 0, wq_out, C_, 0, 0, b_out, hbuf, C_, 0, 0,
      BT, C_, C_, 1, hidden, nullptr, nullptr, 0.f);

  // LN2 (bf16 out) + fq
  k_ln<<<BT, 256, 0, stream>>>(hbuf, ln2g, ln2b, x1, sc + 6);
  k_quant_b<<<512, 256, 0, stream>>>(x1, xq, BT * C_ / 8, sc + 6);

  // y1 = gelu(xq @ wq_w1^T + b1) -> bf16 [4096,4096], + absmax
  k_gemm<128, 128, 2, true><<<dim3(32, 32, 1), 256, 0, stream>>>(
      xq, C_, 0, 0, wq_w1, C_, 0, 0, b1, S, I_, 0, 0,
      BT, I_, C_, 1, nullptr, sc + 7, nullptr, 0.f);

  k_quant_bf16<<<512, 256, 0, stream>>>(S, BT * I_ / 8, sc + 7);

  // out = h + y1q @ wq_w2^T + b2 -> f32 d_out
  k_gemm<64, 128, 3, true><<<dim3(8, 64, 1), 256, 0, stream>>>(
      S, I_, 0, 0, wq_w2, I_, 0, 0, b2, d_out, C_, 0, 0,
      BT, C_, I_, 1, hbuf, nullptr, nullptr, 0.f);
}

// Round 10
// 361.285 us; speedup vs baseline: 1.0492x; 1.0492x over previous
//
#include <hip/hip_runtime.h>

typedef __attribute__((ext_vector_type(8))) short bf16x8;
typedef __attribute__((ext_vector_type(4))) float f32x4;
typedef unsigned short u16;
typedef unsigned int u32;

#define B_ 8
#define T_ 512
#define C_ 1024
#define I_ 4096
#define H_ 16
#define Dh_ 64
#define BT (B_*T_)
#define NH (B_*H_)

// ---------------- helpers ----------------
__device__ __forceinline__ float bf2f(u16 u) {
  return __uint_as_float(((u32)u) << 16);
}
__device__ __forceinline__ u16 f2bf(float f) {
  u32 u = __float_as_uint(f);
  u32 r = u + 0x7FFFu + ((u >> 16) & 1u);
  return (u16)(r >> 16);
}
__device__ __forceinline__ float wredMax(float v) {
#pragma unroll
  for (int o = 32; o; o >>= 1) v = fmaxf(v, __shfl_xor(v, o));
  return v;
}
__device__ __forceinline__ float wredSum(float v) {
#pragma unroll
  for (int o = 32; o; o >>= 1) v += __shfl_xor(v, o);
  return v;
}
// Conditional atomic: only RMW if our value beats the currently visible max.
// Stale reads are always <= true max (monotone), so skipping is safe.
__device__ __forceinline__ void condAtomicMax(u32* amax, float bm) {
  u32 b = __float_as_uint(bm);  // bm >= 0 so uint compare == float compare
  if (b > *(volatile u32*)amax) atomicMax(amax, b);
}
// global -> LDS direct copy, 16B per lane; lds dest is wave-uniform base,
// lane l lands at base + l*16 bytes.
__device__ __forceinline__ void gload16(const void* g, void* l) {
  __builtin_amdgcn_global_load_lds((const __attribute__((address_space(1))) void*)g,
                                   (__attribute__((address_space(3))) void*)l, 16, 0, 0);
}

// ---------------- small kernels ----------------
__global__ void k_init(u32* s) { if (threadIdx.x < 16) s[threadIdx.x] = 0u; }

// absmax of 4 independent f32 arrays -> amax[0..3]
__global__ __launch_bounds__(256) void k_absmax4(
    const float* __restrict__ p0, int n0,
    const float* __restrict__ p1, int n1,
    const float* __restrict__ p2, int n2,
    const float* __restrict__ p3, int n3,
    u32* __restrict__ amax) {
  int stride = gridDim.x * blockDim.x;
  int gid = blockIdx.x * blockDim.x + threadIdx.x;
  float m0 = 0.f, m1 = 0.f, m2 = 0.f, m3 = 0.f;
  for (int i = gid; i < n0; i += stride) {
    float4 v = ((const float4*)p0)[i];
    m0 = fmaxf(m0, fmaxf(fmaxf(fabsf(v.x), fabsf(v.y)), fmaxf(fabsf(v.z), fabsf(v.w))));
  }
  for (int i = gid; i < n1; i += stride) {
    float4 v = ((const float4*)p1)[i];
    m1 = fmaxf(m1, fmaxf(fmaxf(fabsf(v.x), fabsf(v.y)), fmaxf(fabsf(v.z), fabsf(v.w))));
  }
  for (int i = gid; i < n2; i += stride) {
    float4 v = ((const float4*)p2)[i];
    m2 = fmaxf(m2, fmaxf(fmaxf(fabsf(v.x), fabsf(v.y)), fmaxf(fabsf(v.z), fabsf(v.w))));
  }
  for (int i = gid; i < n3; i += stride) {
    float4 v = ((const float4*)p3)[i];
    m3 = fmaxf(m3, fmaxf(fmaxf(fabsf(v.x), fabsf(v.y)), fmaxf(fabsf(v.z), fabsf(v.w))));
  }
  m0 = wredMax(m0); m1 = wredMax(m1); m2 = wredMax(m2); m3 = wredMax(m3);
  __shared__ float red[4][4];
  int wid = threadIdx.x >> 6, lane = threadIdx.x & 63;
  if (lane == 0) { red[wid][0] = m0; red[wid][1] = m1; red[wid][2] = m2; red[wid][3] = m3; }
  __syncthreads();
  if (threadIdx.x < 4) {
    int j = threadIdx.x;
    float bm = fmaxf(fmaxf(red[0][j], red[1][j]), fmaxf(red[2][j], red[3][j]));
    condAtomicMax(amax + j, bm);
  }
}

__device__ __forceinline__ float fq1(float v, float s, float inv) {
  return fminf(fmaxf(rintf(v * inv), -127.f), 127.f) * s;
}

// fake-quant 4 independent f32 arrays -> bf16, scales from amax[0..3]
__global__ __launch_bounds__(256) void k_quant4(
    const float* __restrict__ p0, u16* __restrict__ q0, int n0,
    const float* __restrict__ p1, u16* __restrict__ q1, int n1,
    const float* __restrict__ p2, u16* __restrict__ q2, int n2,
    const float* __restrict__ p3, u16* __restrict__ q3, int n3,
    const u32* __restrict__ amax) {
  int stride = gridDim.x * blockDim.x;
  int gid = blockIdx.x * blockDim.x + threadIdx.x;
#define QLOOP(p, q, n, slot)                                                       \
  {                                                                                \
    float s = fmaxf(__uint_as_float(amax[slot]) / 127.0f, 1e-8f);                  \
    float inv = 1.0f / s;                                                          \
    for (int i = gid; i < n; i += stride) {                                        \
      float4 v = ((const float4*)p)[i];                                            \
      ushort4 o;                                                                   \
      o.x = f2bf(fq1(v.x, s, inv));                                                \
      o.y = f2bf(fq1(v.y, s, inv));                                                \
      o.z = f2bf(fq1(v.z, s, inv));                                                \
      o.w = f2bf(fq1(v.w, s, inv));                                                \
      ((ushort4*)q)[i] = o;                                                        \
    }                                                                              \
  }
  QLOOP(p0, q0, n0, 0)
  QLOOP(p1, q1, n1, 1)
  QLOOP(p2, q2, n2, 2)
  QLOOP(p3, q3, n3, 3)
#undef QLOOP
}

// fake-quant bf16 src -> bf16 dst (different buffers)
__global__ __launch_bounds__(256) void k_quant_b(const u16* __restrict__ x, u16* __restrict__ q, int n8,
                                                 const u32* __restrict__ amax) {
  float s = fmaxf(__uint_as_float(*amax) / 127.0f, 1e-8f);
  float inv = 1.0f / s;
  int stride = gridDim.x * blockDim.x;
  for (int i = blockIdx.x * blockDim.x + threadIdx.x; i < n8; i += stride) {
    uint4 d = ((const uint4*)x)[i];
    u16* e = (u16*)&d;
#pragma unroll
    for (int j = 0; j < 8; j++) e[j] = f2bf(fq1(bf2f(e[j]), s, inv));
    ((uint4*)q)[i] = d;
  }
}

// fake-quant bf16 in-place
__global__ __launch_bounds__(256) void k_quant_bf16(u16* __restrict__ x, int n8, const u32* __restrict__ amax) {
  float s = fmaxf(__uint_as_float(*amax) / 127.0f, 1e-8f);
  float inv = 1.0f / s;
  int stride = gridDim.x * blockDim.x;
  for (int i = blockIdx.x * blockDim.x + threadIdx.x; i < n8; i += stride) {
    uint4 d = ((uint4*)x)[i];
    u16* e = (u16*)&d;
#pragma unroll
    for (int j = 0; j < 8; j++) e[j] = f2bf(fq1(bf2f(e[j]), s, inv));
    ((uint4*)x)[i] = d;
  }
}

// LayerNorm row (C=1024) -> bf16 out + global absmax (block-reduced)
__global__ __launch_bounds__(256) void k_ln(const float* __restrict__ x, const float* __restrict__ g,
                                            const float* __restrict__ b, u16* __restrict__ y,
                                            u32* __restrict__ amax) {
  int row = blockIdx.x;
  int t = threadIdx.x;
  float4 v = ((const float4*)(x + (long)row * C_))[t];
  float s1 = v.x + v.y + v.z + v.w;
  float s2 = v.x * v.x + v.y * v.y + v.z * v.z + v.w * v.w;
  s1 = wredSum(s1);
  s2 = wredSum(s2);
  __shared__ float red[8];
  int wid = t >> 6, lane = t & 63;
  if (lane == 0) { red[wid] = s1; red[4 + wid] = s2; }
  __syncthreads();
  s1 = red[0] + red[1] + red[2] + red[3];
  s2 = red[4] + red[5] + red[6] + red[7];
  float mean = s1 * (1.0f / C_);
  float var = s2 * (1.0f / C_) - mean * mean;
  float inv = rsqrtf(var + 1e-5f);
  float4 gv = ((const float4*)g)[t];
  float4 bv = ((const float4*)b)[t];
  float4 o;
  o.x = (v.x - mean) * inv * gv.x + bv.x;
  o.y = (v.y - mean) * inv * gv.y + bv.y;
  o.z = (v.z - mean) * inv * gv.z + bv.z;
  o.w = (v.w - mean) * inv * gv.w + bv.w;
  ushort4 ob;
  ob.x = f2bf(o.x); ob.y = f2bf(o.y); ob.z = f2bf(o.z); ob.w = f2bf(o.w);
  ((ushort4*)(y + (long)row * C_))[t] = ob;
  float m = fmaxf(fmaxf(fabsf(o.x), fabsf(o.y)), fmaxf(fabsf(o.z), fabsf(o.w)));
  m = wredMax(m);
  __syncthreads();  // all threads done reading red[] for the sums
  if (lane == 0) red[wid] = m;
  __syncthreads();
  if (t == 0) {
    float bm = fmaxf(fmaxf(red[0], red[1]), fmaxf(red[2], red[3]));
    condAtomicMax(amax, bm);
  }
}

// softmax over rows of 512, bf16 in-place; one wave per row
__global__ __launch_bounds__(256) void k_softmax(u16* __restrict__ S) {
  int r = blockIdx.x * 4 + (threadIdx.x >> 6);
  int lane = threadIdx.x & 63;
  u16* row = S + (long)r * T_ + lane * 8;
  uint4 d = *(const uint4*)row;
  u16* e = (u16*)&d;
  float v[8];
  float mx = -3.0e38f;
#pragma unroll
  for (int j = 0; j < 8; j++) { v[j] = bf2f(e[j]); mx = fmaxf(mx, v[j]); }
  mx = wredMax(mx);
  float sum = 0.f;
#pragma unroll
  for (int j = 0; j < 8; j++) { v[j] = expf(v[j] - mx); sum += v[j]; }
  sum = wredSum(sum);
  float inv = 1.0f / sum;
#pragma unroll
  for (int j = 0; j < 8; j++) e[j] = f2bf(v[j] * inv);
  *(uint4*)row = d;
}

// ---------------- unified MFMA GEMM ----------------
// C[M,N] = A[M,K] * B^T + epilogue.  B normally [N,K] row-major; EPI==5: B is [K,N].
// BK=64 (128B rows) with XOR slot-swizzle: element (r, slot) stored at
// phys slot = slot ^ (r&7).  Staging via global_load_lds with PRE-SWIZZLED
// per-lane global source (linear LDS dest); ds_read uses the same XOR.
// DOUBLE-BUFFERED with COUNTED vmcnt (T3+T4): per K-step
//   {STAGE(t+1) -> s_waitcnt vmcnt(NLD) -> s_barrier -> MFMA(t) -> s_barrier}
// so tile t+1's loads stay in flight across the barrier and the compute phase.
// NLD = loads/wave per stage.  EPI5 uses vmcnt(4)+lgkmcnt(0) (ds_write staging).
// SWZ: bijective XCD chunk-swizzle of (bx,by) for L2 A-panel locality.
// EPI: 0 = +bias -> bf16
//      1 = +bias +resid(f32) -> f32
//      2 = +bias, gelu(tanh-form), absmax -> bf16
//      3 = +bias +resid(f32) -> f32 (final output)
//      4 = *scale + mask-ext -> bf16 (scores)
//      5 = absmax -> bf16 (PV; B in [K,N])
template <int BM, int BN, int EPI, bool SWZ>
__global__ __launch_bounds__(256) void k_gemm(
    const u16* __restrict__ A, int lda, long sAb, long sAh,
    const u16* __restrict__ Bm, int ldb, long sBb, long sBh,
    const float* __restrict__ bias,
    void* __restrict__ Cp, int ldc, long sCb, long sCh,
    int M, int N, int K, int bH,
    const float* __restrict__ resid,
    u32* __restrict__ amax,
    const float* __restrict__ mask, float scale) {
  constexpr int BK = 64;
  constexpr int MF = (BM / 2) / 16;
  constexpr int NF = (BN / 2) / 16;
  __shared__ u16 As[2][BM * BK];
  __shared__ u16 Bs[2][BN * BK];
  const int tid = threadIdx.x;
  const int wid = tid >> 6, lane = tid & 63;
  const int wr = wid >> 1, wc = wid & 1;
  const int bz = blockIdx.z;
  const int bb = bz / bH, hh = bz % bH;

  int bx = blockIdx.x, by = blockIdx.y;
  if (SWZ) {
    int gx = gridDim.x;
    int nwg = gx * gridDim.y;       // must be % 8 == 0 (all SWZ call sites are)
    int bid = by * gx + bx;
    int cpx = nwg >> 3;
    int swz = (bid & 7) * cpx + (bid >> 3);
    bx = swz % gx;
    by = swz / gx;
  }

  const u16* Ab = A + bb * sAb + hh * sAh + (long)by * BM * lda;
  const u16* Bb;
  if (EPI == 5)
    Bb = Bm + bb * sBb + hh * sBh + bx * BN;  // [K,N]: column offset
  else
    Bb = Bm + bb * sBb + hh * sBh + (long)bx * BN * ldb;

  f32x4 acc[MF][NF];
#pragma unroll
  for (int m = 0; m < MF; m++)
#pragma unroll
    for (int n = 0; n < NF; n++) acc[m][n] = (f32x4){0.f, 0.f, 0.f, 0.f};

  const int lr = lane & 15;
  // pre-swizzled staging source offsets (stripe base is 8-row aligned, so
  // row&7 == lane>>3 independent of stripe)
  const int l8 = lane >> 3;              // row within 8-row stripe
  const int s8 = (lane & 7) ^ l8;        // swizzled slot to fetch
  const long aoff = (long)l8 * lda + (s8 << 3);
  const long boff = (long)l8 * ldb + (s8 << 3);

  // ---- staging (issue only; no waits) ----
  auto stageAB = [&](int buf, int k0) {
#pragma unroll
    for (int i = 0; i < BM / 32; ++i) {
      int R0 = wid * (BM / 4) + i * 8;
      gload16(Ab + (long)R0 * lda + k0 + aoff, &As[buf][R0 * 64]);
    }
    if (EPI == 5) {
      // Bs[n][kk] = Bb[(k0+kk)*ldb + n], swizzled scatter (BN==64)
      int kk = tid >> 2;
      int sp = kk >> 3, k7 = kk & 7;
#pragma unroll
      for (int h = 0; h < 2; ++h) {
        int n0 = ((tid & 3) + h * 4) * 8;
        uint4 t4 = *(const uint4*)(Bb + (long)(k0 + kk) * ldb + n0);
        u16* tv = (u16*)&t4;
#pragma unroll
        for (int j = 0; j < 8; j++)
          Bs[buf][(n0 + j) * 64 + ((sp ^ j) << 3) + k7] = tv[j];
      }
    } else {
#pragma unroll
      for (int i = 0; i < BN / 32; ++i) {
        int R0 = wid * (BN / 4) + i * 8;
        gload16(Bb + (long)R0 * ldb + k0 + boff, &Bs[buf][R0 * 64]);
      }
    }
  };

  // counted wait: tile t's loads retired, tile t+1's (NLD per wave) in flight
  auto waitCounted = [&]() {
    if constexpr (EPI == 5) {
      asm volatile("s_waitcnt vmcnt(4) lgkmcnt(0)" ::: "memory");
    } else if constexpr ((BM / 32 + BN / 32) == 8) {
      asm volatile("s_waitcnt vmcnt(8)" ::: "memory");
    } else {
      asm volatile("s_waitcnt vmcnt(6)" ::: "memory");
    }
  };

  // ---- compute one K-tile from buf ----
  auto computeK = [&](int buf) {
#pragma unroll
    for (int kk = 0; kk < 2; ++kk) {
      const int sl = (kk << 2) + (lane >> 4);
      const int sf = (sl ^ (lr & 7)) << 3;
      bf16x8 af[MF], bfr[NF];
#pragma unroll
      for (int m = 0; m < MF; m++)
        af[m] = *(const bf16x8*)&As[buf][(wr * (BM / 2) + m * 16 + lr) * 64 + sf];
#pragma unroll
      for (int n = 0; n < NF; n++)
        bfr[n] = *(const bf16x8*)&Bs[buf][(wc * (BN / 2) + n * 16 + lr) * 64 + sf];
      __builtin_amdgcn_s_setprio(1);
#pragma unroll
      for (int m = 0; m < MF; m++)
#pragma unroll
        for (int n = 0; n < NF; n++)
          acc[m][n] = __builtin_amdgcn_mfma_f32_16x16x32_bf16(af[m], bfr[n], acc[m][n], 0, 0, 0);
      __builtin_amdgcn_s_setprio(0);
    }
  };

  const int nt = K / BK;
  stageAB(0, 0);
  int cur = 0;
  for (int t = 0; t < nt; ++t) {
    if (t + 1 < nt) {
      stageAB(cur ^ 1, (t + 1) * BK);   // issue next tile; stays in flight
      waitCounted();                    // tile t landed; t+1 still outstanding
    } else {
      asm volatile("s_waitcnt vmcnt(0) lgkmcnt(0)" ::: "memory");
    }
    __builtin_amdgcn_s_barrier();       // buf[cur] ready for all waves
    computeK(cur);
    if (t + 1 < nt)
      __builtin_amdgcn_s_barrier();     // all waves done reading buf[cur]
    cur ^= 1;
  }

  const int rowBase = by * BM + wr * (BM / 2);
  const int colBase = bx * BN + wc * (BN / 2);
  const long cb = bb * sCb + hh * sCh;
  float lmax = 0.f;
#pragma unroll
  for (int m = 0; m < MF; m++) {
    int row0 = rowBase + m * 16 + (lane >> 4) * 4;
#pragma unroll
    for (int n = 0; n < NF; n++) {
      int col = colBase + n * 16 + lr;
      float bs = 0.f, ext = 0.f;
      if (EPI == 0 || EPI == 1 || EPI == 2 || EPI == 3) bs = bias[col];
      if (EPI == 4) ext = (1.0f - mask[bb * T_ + col]) * -10000.0f;
#pragma unroll
      for (int j = 0; j < 4; j++) {
        int row = row0 + j;
        long idx = cb + (long)row * ldc + col;
        float v = acc[m][n][j];
        if (EPI == 0) {
          ((u16*)Cp)[idx] = f2bf(v + bs);
        } else if (EPI == 1) {
          ((float*)Cp)[idx] = v + bs + resid[idx];
        } else if (EPI == 2) {
          v += bs;
          // gelu tanh-form: x * sigmoid(2*(0.79788456*(x+0.044715 x^3)))
          float x2 = v * v;
          float e = __expf(v * fmaf(-0.0713548755f, x2, -1.5957691216f));
          v = v * __builtin_amdgcn_rcpf(1.0f + e);
          lmax = fmaxf(fmaxf(lmax, v), 0.0f - v);  // v_max3
          ((u16*)Cp)[idx] = f2bf(v);
        } else if (EPI == 3) {
          ((float*)Cp)[idx] = v + bs + resid[idx];
        } else if (EPI == 4) {
          ((u16*)Cp)[idx] = f2bf(v * scale + ext);
        } else {
          lmax = fmaxf(fmaxf(lmax, v), 0.0f - v);  // v_max3
          ((u16*)Cp)[idx] = f2bf(v);
        }
      }
    }
  }
  if (EPI == 2 || EPI == 5) {
    __shared__ float redm[4];
    float wm = wredMax(lmax);
    if (lane == 0) redm[wid] = wm;
    __syncthreads();
    if (tid == 0) {
      float bm = fmaxf(fmaxf(redm[0], redm[1]), fmaxf(redm[2], redm[3]));
      condAtomicMax(amax, bm);
    }
  }
}

// ---------------- host ----------------
extern "C" void kernel_launch(void* const* d_in, const int* in_sizes, int n_in,
                              void* d_out, int out_size, void* d_ws, size_t ws_size,
                              hipStream_t stream) {
  const float* hidden = (const float*)d_in[0];
  const float* mask = (const float*)d_in[1];
  const float* ln1g = (const float*)d_in[2];
  const float* ln1b = (const float*)d_in[3];
  const float* ln2g = (const float*)d_in[4];
  const float* ln2b = (const float*)d_in[5];
  const float* w_qkv = (const float*)d_in[6];
  const float* b_qkv = (const float*)d_in[7];
  const float* w_out = (const float*)d_in[8];
  const float* b_out = (const float*)d_in[9];
  const float* w1 = (const float*)d_in[10];
  const float* b1 = (const float*)d_in[11];
  const float* w2 = (const float*)d_in[12];
  const float* b2 = (const float*)d_in[13];

  char* ws = (char*)d_ws;
  u32* sc = (u32*)ws;  // [0]wqkv [1]wout [2]w1 [3]w2 [4]x1 [5]O [6]x2 [7]y1
  u16* wq_qkv = (u16*)(ws + 256);
  u16* wq_out = (u16*)(ws + 6291712);
  u16* wq_w1 = (u16*)(ws + 8388864);
  u16* wq_w2 = (u16*)(ws + 16777472);
  u16* x1 = (u16*)(ws + 25166080);       // LN output, bf16 (also x2)
  u16* xq = (u16*)(ws + 41943296);       // also x2q
  u16* qkv = (u16*)(ws + 50331904);
  u16* S = (u16*)(ws + 75497728);        // scores/P; later y1 (raw+quant)
  u16* O = (u16*)(ws + 142606592);
  float* hbuf = (float*)(ws + 150995200);
  // total ws use: 167,772,416 bytes

  k_init<<<1, 64, 0, stream>>>(sc);

  // weight fake-quant (merged: 2 launches)
  k_absmax4<<<512, 256, 0, stream>>>(
      w_qkv, 3 * C_ * C_ / 4, w_out, C_ * C_ / 4, w1, I_ * C_ / 4, w2, C_ * I_ / 4, sc);
  k_quant4<<<512, 256, 0, stream>>>(
      w_qkv, wq_qkv, 3 * C_ * C_ / 4, w_out, wq_out, C_ * C_ / 4,
      w1, wq_w1, I_ * C_ / 4, w2, wq_w2, C_ * I_ / 4, sc);

  // LN1 (bf16 out) + fq(x)
  k_ln<<<BT, 256, 0, stream>>>(hidden, ln1g, ln1b, x1, sc + 4);
  k_quant_b<<<512, 256, 0, stream>>>(x1, xq, BT * C_ / 8, sc + 4);

  // qkv = xq @ wq_qkv^T + b  -> bf16 [4096,3072]
  k_gemm<128, 128, 0, true><<<dim3(24, 32, 1), 256, 0, stream>>>(
      xq, C_, 0, 0, wq_qkv, C_, 0, 0, b_qkv, qkv, 3 * C_, 0, 0,
      BT, 3 * C_, C_, 1, nullptr, nullptr, nullptr, 0.f);

  // scores = Q K^T * scale + ext -> bf16 [128][512][512]
  k_gemm<128, 128, 4, false><<<dim3(4, 4, NH), 256, 0, stream>>>(
      qkv, 3 * C_, (long)T_ * 3 * C_, Dh_,
      qkv + C_, 3 * C_, (long)T_ * 3 * C_, Dh_,
      nullptr,
      S, T_, (long)H_ * T_ * T_, (long)T_ * T_,
      T_, T_, Dh_, H_, nullptr, nullptr, mask, 0.125f);

  k_softmax<<<NH * T_ / 4, 256, 0, stream>>>(S);

  // O = P @ V  (B in [K,N])  -> bf16 [4096,1024] in (b,t,h*64+d) layout, + absmax
  k_gemm<128, 64, 5, false><<<dim3(1, 4, NH), 256, 0, stream>>>(
      S, T_, (long)H_ * T_ * T_, (long)T_ * T_,
      qkv + 2 * C_, 3 * C_, (long)T_ * 3 * C_, Dh_,
      nullptr,
      O, C_, (long)T_ * C_, (long)Dh_,
      T_, Dh_, T_, H_, nullptr, sc + 5, nullptr, 0.f);

  k_quant_bf16<<<512, 256, 0, stream>>>(O, BT * C_ / 8, sc + 5);

  // h = hidden + Oq @ wq_out^T + b  -> f32
  k_gemm<64, 128, 1, true><<<dim3(8, 64, 1), 256, 0, stream>>>(
      O, C_, 0, 0, wq_out, C_, 0, 0, b_out, hbuf, C_, 0, 0,
      BT, C_, C_, 1, hidden, nullptr, nullptr, 0.f);

  // LN2 (bf16 out) + fq
  k_ln<<<BT, 256, 0, stream>>>(hbuf, ln2g, ln2b, x1, sc + 6);
  k_quant_b<<<512, 256, 0, stream>>>(x1, xq, BT * C_ / 8, sc + 6);

  // y1 = gelu(xq @ wq_w1^T + b1) -> bf16 [4096,4096], + absmax
  k_gemm<128, 128, 2, true><<<dim3(32, 32, 1), 256, 0, stream>>>(
      xq, C_, 0, 0, wq_w1, C_, 0, 0, b1, S, I_, 0, 0,
      BT, I_, C_, 1, nullptr, sc + 7, nullptr, 0.f);

  k_quant_bf16<<<512, 256, 0, stream>>>(S, BT * I_ / 8, sc + 7);

  // out = h + y1q @ wq_w2^T + b2 -> f32 d_out
  k_gemm<64, 128, 3, true><<<dim3(8, 64, 1), 256, 0, stream>>>(
      S, I_, 0, 0, wq_w2, I_, 0, 0, b2, d_out, C_, 0, 0,
      BT, C_, I_, 1, hbuf, nullptr, nullptr, 0.f);
}

// Round 11
// 339.245 us; speedup vs baseline: 1.1174x; 1.0650x over previous
//
#include <hip/hip_runtime.h>

typedef __attribute__((ext_vector_type(8))) short bf16x8;
typedef __attribute__((ext_vector_type(4))) float f32x4;
typedef unsigned short u16;
typedef unsigned int u32;

#define B_ 8
#define T_ 512
#define C_ 1024
#define I_ 4096
#define H_ 16
#define Dh_ 64
#define BT (B_*T_)
#define NH (B_*H_)

// ---------------- helpers ----------------
__device__ __forceinline__ float bf2f(u16 u) {
  return __uint_as_float(((u32)u) << 16);
}
__device__ __forceinline__ u16 f2bf(float f) {
  u32 u = __float_as_uint(f);
  u32 r = u + 0x7FFFu + ((u >> 16) & 1u);
  return (u16)(r >> 16);
}
__device__ __forceinline__ float wredMax(float v) {
#pragma unroll
  for (int o = 32; o; o >>= 1) v = fmaxf(v, __shfl_xor(v, o));
  return v;
}
__device__ __forceinline__ float wredSum(float v) {
#pragma unroll
  for (int o = 32; o; o >>= 1) v += __shfl_xor(v, o);
  return v;
}
// Conditional atomic: only RMW if our value beats the currently visible max.
// Stale reads are always <= true max (monotone), so skipping is safe.
__device__ __forceinline__ void condAtomicMax(u32* amax, float bm) {
  u32 b = __float_as_uint(bm);  // bm >= 0 so uint compare == float compare
  if (b > *(volatile u32*)amax) atomicMax(amax, b);
}
// global -> LDS direct copy, 16B per lane; lds dest is wave-uniform base,
// lane l lands at base + l*16 bytes.
__device__ __forceinline__ void gload16(const void* g, void* l) {
  __builtin_amdgcn_global_load_lds((const __attribute__((address_space(1))) void*)g,
                                   (__attribute__((address_space(3))) void*)l, 16, 0, 0);
}

// ---------------- small kernels ----------------
__global__ void k_init(u32* s) { if (threadIdx.x < 16) s[threadIdx.x] = 0u; }

// absmax of 4 independent f32 arrays -> amax[0..3]
__global__ __launch_bounds__(256) void k_absmax4(
    const float* __restrict__ p0, int n0,
    const float* __restrict__ p1, int n1,
    const float* __restrict__ p2, int n2,
    const float* __restrict__ p3, int n3,
    u32* __restrict__ amax) {
  int stride = gridDim.x * blockDim.x;
  int gid = blockIdx.x * blockDim.x + threadIdx.x;
  float m0 = 0.f, m1 = 0.f, m2 = 0.f, m3 = 0.f;
  for (int i = gid; i < n0; i += stride) {
    float4 v = ((const float4*)p0)[i];
    m0 = fmaxf(m0, fmaxf(fmaxf(fabsf(v.x), fabsf(v.y)), fmaxf(fabsf(v.z), fabsf(v.w))));
  }
  for (int i = gid; i < n1; i += stride) {
    float4 v = ((const float4*)p1)[i];
    m1 = fmaxf(m1, fmaxf(fmaxf(fabsf(v.x), fabsf(v.y)), fmaxf(fabsf(v.z), fabsf(v.w))));
  }
  for (int i = gid; i < n2; i += stride) {
    float4 v = ((const float4*)p2)[i];
    m2 = fmaxf(m2, fmaxf(fmaxf(fabsf(v.x), fabsf(v.y)), fmaxf(fabsf(v.z), fabsf(v.w))));
  }
  for (int i = gid; i < n3; i += stride) {
    float4 v = ((const float4*)p3)[i];
    m3 = fmaxf(m3, fmaxf(fmaxf(fabsf(v.x), fabsf(v.y)), fmaxf(fabsf(v.z), fabsf(v.w))));
  }
  m0 = wredMax(m0); m1 = wredMax(m1); m2 = wredMax(m2); m3 = wredMax(m3);
  __shared__ float red[4][4];
  int wid = threadIdx.x >> 6, lane = threadIdx.x & 63;
  if (lane == 0) { red[wid][0] = m0; red[wid][1] = m1; red[wid][2] = m2; red[wid][3] = m3; }
  __syncthreads();
  if (threadIdx.x < 4) {
    int j = threadIdx.x;
    float bm = fmaxf(fmaxf(red[0][j], red[1][j]), fmaxf(red[2][j], red[3][j]));
    condAtomicMax(amax + j, bm);
  }
}

__device__ __forceinline__ float fq1(float v, float s, float inv) {
  return fminf(fmaxf(rintf(v * inv), -127.f), 127.f) * s;
}

// fake-quant 4 independent f32 arrays -> bf16, scales from amax[0..3]
__global__ __launch_bounds__(256) void k_quant4(
    const float* __restrict__ p0, u16* __restrict__ q0, int n0,
    const float* __restrict__ p1, u16* __restrict__ q1, int n1,
    const float* __restrict__ p2, u16* __restrict__ q2, int n2,
    const float* __restrict__ p3, u16* __restrict__ q3, int n3,
    const u32* __restrict__ amax) {
  int stride = gridDim.x * blockDim.x;
  int gid = blockIdx.x * blockDim.x + threadIdx.x;
#define QLOOP(p, q, n, slot)                                                       \
  {                                                                                \
    float s = fmaxf(__uint_as_float(amax[slot]) / 127.0f, 1e-8f);                  \
    float inv = 1.0f / s;                                                          \
    for (int i = gid; i < n; i += stride) {                                        \
      float4 v = ((const float4*)p)[i];                                            \
      ushort4 o;                                                                   \
      o.x = f2bf(fq1(v.x, s, inv));                                                \
      o.y = f2bf(fq1(v.y, s, inv));                                                \
      o.z = f2bf(fq1(v.z, s, inv));                                                \
      o.w = f2bf(fq1(v.w, s, inv));                                                \
      ((ushort4*)q)[i] = o;                                                        \
    }                                                                              \
  }
  QLOOP(p0, q0, n0, 0)
  QLOOP(p1, q1, n1, 1)
  QLOOP(p2, q2, n2, 2)
  QLOOP(p3, q3, n3, 3)
#undef QLOOP
}

// fake-quant bf16 src -> bf16 dst (different buffers)
__global__ __launch_bounds__(256) void k_quant_b(const u16* __restrict__ x, u16* __restrict__ q, int n8,
                                                 const u32* __restrict__ amax) {
  float s = fmaxf(__uint_as_float(*amax) / 127.0f, 1e-8f);
  float inv = 1.0f / s;
  int stride = gridDim.x * blockDim.x;
  for (int i = blockIdx.x * blockDim.x + threadIdx.x; i < n8; i += stride) {
    uint4 d = ((const uint4*)x)[i];
    u16* e = (u16*)&d;
#pragma unroll
    for (int j = 0; j < 8; j++) e[j] = f2bf(fq1(bf2f(e[j]), s, inv));
    ((uint4*)q)[i] = d;
  }
}

// fake-quant bf16 in-place
__global__ __launch_bounds__(256) void k_quant_bf16(u16* __restrict__ x, int n8, const u32* __restrict__ amax) {
  float s = fmaxf(__uint_as_float(*amax) / 127.0f, 1e-8f);
  float inv = 1.0f / s;
  int stride = gridDim.x * blockDim.x;
  for (int i = blockIdx.x * blockDim.x + threadIdx.x; i < n8; i += stride) {
    uint4 d = ((uint4*)x)[i];
    u16* e = (u16*)&d;
#pragma unroll
    for (int j = 0; j < 8; j++) e[j] = f2bf(fq1(bf2f(e[j]), s, inv));
    ((uint4*)x)[i] = d;
  }
}

// LayerNorm row (C=1024) -> bf16 out + global absmax (block-reduced)
__global__ __launch_bounds__(256) void k_ln(const float* __restrict__ x, const float* __restrict__ g,
                                            const float* __restrict__ b, u16* __restrict__ y,
                                            u32* __restrict__ amax) {
  int row = blockIdx.x;
  int t = threadIdx.x;
  float4 v = ((const float4*)(x + (long)row * C_))[t];
  float s1 = v.x + v.y + v.z + v.w;
  float s2 = v.x * v.x + v.y * v.y + v.z * v.z + v.w * v.w;
  s1 = wredSum(s1);
  s2 = wredSum(s2);
  __shared__ float red[8];
  int wid = t >> 6, lane = t & 63;
  if (lane == 0) { red[wid] = s1; red[4 + wid] = s2; }
  __syncthreads();
  s1 = red[0] + red[1] + red[2] + red[3];
  s2 = red[4] + red[5] + red[6] + red[7];
  float mean = s1 * (1.0f / C_);
  float var = s2 * (1.0f / C_) - mean * mean;
  float inv = rsqrtf(var + 1e-5f);
  float4 gv = ((const float4*)g)[t];
  float4 bv = ((const float4*)b)[t];
  float4 o;
  o.x = (v.x - mean) * inv * gv.x + bv.x;
  o.y = (v.y - mean) * inv * gv.y + bv.y;
  o.z = (v.z - mean) * inv * gv.z + bv.z;
  o.w = (v.w - mean) * inv * gv.w + bv.w;
  ushort4 ob;
  ob.x = f2bf(o.x); ob.y = f2bf(o.y); ob.z = f2bf(o.z); ob.w = f2bf(o.w);
  ((ushort4*)(y + (long)row * C_))[t] = ob;
  float m = fmaxf(fmaxf(fabsf(o.x), fabsf(o.y)), fmaxf(fabsf(o.z), fabsf(o.w)));
  m = wredMax(m);
  __syncthreads();  // all threads done reading red[] for the sums
  if (lane == 0) red[wid] = m;
  __syncthreads();
  if (t == 0) {
    float bm = fmaxf(fmaxf(red[0], red[1]), fmaxf(red[2], red[3]));
    condAtomicMax(amax, bm);
  }
}

// ---------------- fused attention ----------------
// One block per (head, q-chunk of 256 rows). K,V for the head live wholly in
// LDS (64 KB each).  Swapped QK^T (mfma(K,Q) -> S^T) so online-softmax state
// is lane-local per q-column; P routed via per-wave LDS [q][kv] (stride 80B);
// PV as mfma(V^T, P^T) -> O^T with V transpose-staged (XOR slot-swizzle on
// both sides).  Zero barriers in the main loop.
__global__ __launch_bounds__(256, 1) void k_attn(
    const u16* __restrict__ qkv, const float* __restrict__ mask,
    u16* __restrict__ O, u32* __restrict__ amax) {
  __shared__ u16 Ke[512 * 64];        // [kv][d-slot swz]  64 KB
  __shared__ u16 Vt[64 * 512];        // [d][kv-slot swz]  64 KB
  __shared__ u16 Pl[4 * 64 * 40];     // per-wave [q][kv], 80B row  20 KB
  __shared__ float extl[512];         // (1-mask)*-1e4     2 KB
  __shared__ float redm[4];
  const int tid = threadIdx.x;
  const int w = tid >> 6, l = tid & 63;
  const int head = blockIdx.x;        // b*16+h
  const int chunk = blockIdx.y;       // 0..1
  const int b = head >> 4, h = head & 15;
  const long rowbase = (long)(b * 512) * (3 * C_);

  // ---- stage K via global_load_lds (pre-swizzled source, linear dest) ----
  {
    const u16* Kg = qkv + rowbase + C_ + h * 64;
    int lr8 = l >> 3;                 // row within 8-row stripe
    int ls = (l & 7) ^ lr8;           // swizzled 16B slot to fetch
    const long koff = (long)lr8 * (3 * C_) + ls * 8;
#pragma unroll
    for (int i = 0; i < 16; ++i) {
      int r0 = w * 128 + i * 8;
      gload16(Kg + (long)r0 * (3 * C_) + koff, &Ke[r0 * 64]);
    }
  }
  // ---- stage V^T via reg path (swizzled scatter) ----
  {
    const u16* Vg = qkv + rowbase + 2 * C_ + h * 64;
    int kvl = tid & 31;
    int d0 = (tid >> 5) * 8;
#pragma unroll 4
    for (int i = 0; i < 16; ++i) {
      int kv = i * 32 + kvl;
      uint4 t4 = *(const uint4*)(Vg + (long)kv * (3 * C_) + d0);
      u16* tv = (u16*)&t4;
      int slot = kv >> 3, within = kv & 7;
#pragma unroll
      for (int j = 0; j < 8; ++j) {
        int d = d0 + j;
        Vt[d * 512 + ((slot ^ (d & 7)) << 3) + within] = tv[j];
      }
    }
  }
  // ---- ext values ----
  {
    const float* mb = mask + b * 512;
    extl[tid] = (1.0f - mb[tid]) * -10000.0f;
    extl[tid + 256] = (1.0f - mb[tid + 256]) * -10000.0f;
  }
  // ---- Q fragments (B-operand of swapped QK^T): Q[q][d] rows in regs ----
  const int qbase = chunk * 256 + w * 64;
  bf16x8 qf[4][2];
  {
    const u16* Qg = qkv + rowbase + h * 64;
#pragma unroll
    for (int qt = 0; qt < 4; ++qt)
#pragma unroll
      for (int dc = 0; dc < 2; ++dc)
        qf[qt][dc] = *(const bf16x8*)(Qg + (long)(qbase + qt * 16 + (l & 15)) * (3 * C_) + dc * 32 + (l >> 4) * 8);
  }
  __syncthreads();  // drains gload16 + ds_writes + makes K/V visible

  f32x4 oacc[4][4];                    // O^T tiles [dt][qt]
  float mrun[4], lrun[4];
#pragma unroll
  for (int qt = 0; qt < 4; ++qt) { mrun[qt] = -3.0e38f; lrun[qt] = 0.f; }
#pragma unroll
  for (int dt = 0; dt < 4; ++dt)
#pragma unroll
    for (int qt = 0; qt < 4; ++qt) oacc[dt][qt] = (f32x4){0.f, 0.f, 0.f, 0.f};

  u16* Pw = &Pl[w * 64 * 40];

  for (int ks = 0; ks < 16; ++ks) {
    // --- QK^T: S^T tiles [kv16 x q16], kv = ks*32 + ... ---
    bf16x8 kf[2][2];
#pragma unroll
    for (int kvt = 0; kvt < 2; ++kvt) {
      int kv = ks * 32 + kvt * 16 + (l & 15);
#pragma unroll
      for (int dc = 0; dc < 2; ++dc) {
        int phys = (dc * 4 + (l >> 4)) ^ (kv & 7);
        kf[kvt][dc] = *(const bf16x8*)&Ke[kv * 64 + phys * 8];
      }
    }
    f32x4 sacc[2][4];
#pragma unroll
    for (int kvt = 0; kvt < 2; ++kvt)
#pragma unroll
      for (int qt = 0; qt < 4; ++qt) {
        f32x4 a = (f32x4){0.f, 0.f, 0.f, 0.f};
        a = __builtin_amdgcn_mfma_f32_16x16x32_bf16(kf[kvt][0], qf[qt][0], a, 0, 0, 0);
        a = __builtin_amdgcn_mfma_f32_16x16x32_bf16(kf[kvt][1], qf[qt][1], a, 0, 0, 0);
        sacc[kvt][qt] = a;
      }
    // scale + mask-ext (kv = row index of S^T = (l>>4)*4 + r)
#pragma unroll
    for (int kvt = 0; kvt < 2; ++kvt) {
      f32x4 ev = *(const f32x4*)&extl[ks * 32 + kvt * 16 + (l >> 4) * 4];
#pragma unroll
      for (int qt = 0; qt < 4; ++qt)
#pragma unroll
        for (int r = 0; r < 4; ++r)
          sacc[kvt][qt][r] = fmaf(sacc[kvt][qt][r], 0.125f, ev[r]);
    }
    // --- online softmax per q-tile (q = qt*16 + (l&15), lane-local state) ---
#pragma unroll
    for (int qt = 0; qt < 4; ++qt) {
      float pm = sacc[0][qt][0];
#pragma unroll
      for (int r = 1; r < 4; ++r) pm = fmaxf(pm, sacc[0][qt][r]);
#pragma unroll
      for (int r = 0; r < 4; ++r) pm = fmaxf(pm, sacc[1][qt][r]);
      pm = fmaxf(pm, __shfl_xor(pm, 16));
      pm = fmaxf(pm, __shfl_xor(pm, 32));
      float mnew = fmaxf(mrun[qt], pm);
      float f = __expf(mrun[qt] - mnew);
      mrun[qt] = mnew;
      float lsum = 0.f;
#pragma unroll
      for (int kvt = 0; kvt < 2; ++kvt)
#pragma unroll
        for (int r = 0; r < 4; ++r) {
          float p = __expf(sacc[kvt][qt][r] - mnew);
          sacc[kvt][qt][r] = p;
          lsum += p;
        }
      lsum += __shfl_xor(lsum, 16);
      lsum += __shfl_xor(lsum, 32);
      lrun[qt] = lrun[qt] * f + lsum;
#pragma unroll
      for (int dt = 0; dt < 4; ++dt)
#pragma unroll
        for (int r = 0; r < 4; ++r) oacc[dt][qt][r] *= f;
      // pack P -> LDS [q][kv]: kv = kvt*16 + (l>>4)*4 + r (consecutive r)
#pragma unroll
      for (int kvt = 0; kvt < 2; ++kvt) {
        u32 p01 = (u32)f2bf(sacc[kvt][qt][0]) | ((u32)f2bf(sacc[kvt][qt][1]) << 16);
        u32 p23 = (u32)f2bf(sacc[kvt][qt][2]) | ((u32)f2bf(sacc[kvt][qt][3]) << 16);
        u16* pr = Pw + (qt * 16 + (l & 15)) * 40 + kvt * 16 + (l >> 4) * 4;
        *(u32*)pr = p01;
        *(u32*)(pr + 2) = p23;
      }
    }
    // --- PV: O^T += V^T * P^T  (A = V^T rows d=l&15; B = P rows q=l&15) ---
    bf16x8 vf[4], pf[4];
#pragma unroll
    for (int dt = 0; dt < 4; ++dt) {
      int d = dt * 16 + (l & 15);
      int phys = (ks * 4 + (l >> 4)) ^ (d & 7);
      vf[dt] = *(const bf16x8*)&Vt[d * 512 + phys * 8];
    }
#pragma unroll
    for (int qt = 0; qt < 4; ++qt)
      pf[qt] = *(const bf16x8*)(Pw + (qt * 16 + (l & 15)) * 40 + (l >> 4) * 8);
#pragma unroll
    for (int dt = 0; dt < 4; ++dt)
#pragma unroll
      for (int qt = 0; qt < 4; ++qt)
        oacc[dt][qt] = __builtin_amdgcn_mfma_f32_16x16x32_bf16(vf[dt], pf[qt], oacc[dt][qt], 0, 0, 0);
  }

  // ---- epilogue: O = O^T / l, absmax, write [b,t][h*64+d] ----
  float lmax = 0.f;
  u16* Ob = O + (long)(b * 512 + qbase) * C_ + h * 64;
#pragma unroll
  for (int qt = 0; qt < 4; ++qt) {
    float inv = 1.0f / lrun[qt];
    long qoff = (long)(qt * 16 + (l & 15)) * C_;
#pragma unroll
    for (int dt = 0; dt < 4; ++dt) {
      int d = dt * 16 + (l >> 4) * 4;
      float v0 = oacc[dt][qt][0] * inv;
      float v1 = oacc[dt][qt][1] * inv;
      float v2 = oacc[dt][qt][2] * inv;
      float v3 = oacc[dt][qt][3] * inv;
      lmax = fmaxf(fmaxf(lmax, fmaxf(fabsf(v0), fabsf(v1))), fmaxf(fabsf(v2), fabsf(v3)));
      u32 a01 = (u32)f2bf(v0) | ((u32)f2bf(v1) << 16);
      u32 a23 = (u32)f2bf(v2) | ((u32)f2bf(v3) << 16);
      *(u32*)(Ob + qoff + d) = a01;
      *(u32*)(Ob + qoff + d + 2) = a23;
    }
  }
  lmax = wredMax(lmax);
  if (l == 0) redm[w] = lmax;
  __syncthreads();
  if (tid == 0)
    condAtomicMax(amax, fmaxf(fmaxf(redm[0], redm[1]), fmaxf(redm[2], redm[3])));
}

// ---------------- unified MFMA GEMM (unchanged from round 10) ----------------
template <int BM, int BN, int EPI, bool SWZ>
__global__ __launch_bounds__(256) void k_gemm(
    const u16* __restrict__ A, int lda, long sAb, long sAh,
    const u16* __restrict__ Bm, int ldb, long sBb, long sBh,
    const float* __restrict__ bias,
    void* __restrict__ Cp, int ldc, long sCb, long sCh,
    int M, int N, int K, int bH,
    const float* __restrict__ resid,
    u32* __restrict__ amax,
    const float* __restrict__ mask, float scale) {
  constexpr int BK = 64;
  constexpr int MF = (BM / 2) / 16;
  constexpr int NF = (BN / 2) / 16;
  __shared__ u16 As[2][BM * BK];
  __shared__ u16 Bs[2][BN * BK];
  const int tid = threadIdx.x;
  const int wid = tid >> 6, lane = tid & 63;
  const int wr = wid >> 1, wc = wid & 1;
  const int bz = blockIdx.z;
  const int bb = bz / bH, hh = bz % bH;

  int bx = blockIdx.x, by = blockIdx.y;
  if (SWZ) {
    int gx = gridDim.x;
    int nwg = gx * gridDim.y;
    int bid = by * gx + bx;
    int cpx = nwg >> 3;
    int swz = (bid & 7) * cpx + (bid >> 3);
    bx = swz % gx;
    by = swz / gx;
  }

  const u16* Ab = A + bb * sAb + hh * sAh + (long)by * BM * lda;
  const u16* Bb = Bm + bb * sBb + hh * sBh + (long)bx * BN * ldb;

  f32x4 acc[MF][NF];
#pragma unroll
  for (int m = 0; m < MF; m++)
#pragma unroll
    for (int n = 0; n < NF; n++) acc[m][n] = (f32x4){0.f, 0.f, 0.f, 0.f};

  const int lr = lane & 15;
  const int l8 = lane >> 3;
  const int s8 = (lane & 7) ^ l8;
  const long aoff = (long)l8 * lda + (s8 << 3);
  const long boff = (long)l8 * ldb + (s8 << 3);

  auto stageAB = [&](int buf, int k0) {
#pragma unroll
    for (int i = 0; i < BM / 32; ++i) {
      int R0 = wid * (BM / 4) + i * 8;
      gload16(Ab + (long)R0 * lda + k0 + aoff, &As[buf][R0 * 64]);
    }
#pragma unroll
    for (int i = 0; i < BN / 32; ++i) {
      int R0 = wid * (BN / 4) + i * 8;
      gload16(Bb + (long)R0 * ldb + k0 + boff, &Bs[buf][R0 * 64]);
    }
  };

  auto waitCounted = [&]() {
    if constexpr ((BM / 32 + BN / 32) == 8) {
      asm volatile("s_waitcnt vmcnt(8)" ::: "memory");
    } else {
      asm volatile("s_waitcnt vmcnt(6)" ::: "memory");
    }
  };

  auto computeK = [&](int buf) {
#pragma unroll
    for (int kk = 0; kk < 2; ++kk) {
      const int sl = (kk << 2) + (lane >> 4);
      const int sf = (sl ^ (lr & 7)) << 3;
      bf16x8 af[MF], bfr[NF];
#pragma unroll
      for (int m = 0; m < MF; m++)
        af[m] = *(const bf16x8*)&As[buf][(wr * (BM / 2) + m * 16 + lr) * 64 + sf];
#pragma unroll
      for (int n = 0; n < NF; n++)
        bfr[n] = *(const bf16x8*)&Bs[buf][(wc * (BN / 2) + n * 16 + lr) * 64 + sf];
      __builtin_amdgcn_s_setprio(1);
#pragma unroll
      for (int m = 0; m < MF; m++)
#pragma unroll
        for (int n = 0; n < NF; n++)
          acc[m][n] = __builtin_amdgcn_mfma_f32_16x16x32_bf16(af[m], bfr[n], acc[m][n], 0, 0, 0);
      __builtin_amdgcn_s_setprio(0);
    }
  };

  const int nt = K / BK;
  stageAB(0, 0);
  int cur = 0;
  for (int t = 0; t < nt; ++t) {
    if (t + 1 < nt) {
      stageAB(cur ^ 1, (t + 1) * BK);
      waitCounted();
    } else {
      asm volatile("s_waitcnt vmcnt(0) lgkmcnt(0)" ::: "memory");
    }
    __builtin_amdgcn_s_barrier();
    computeK(cur);
    if (t + 1 < nt)
      __builtin_amdgcn_s_barrier();
    cur ^= 1;
  }

  const int rowBase = by * BM + wr * (BM / 2);
  const int colBase = bx * BN + wc * (BN / 2);
  const long cb = bb * sCb + hh * sCh;
  float lmax = 0.f;
#pragma unroll
  for (int m = 0; m < MF; m++) {
    int row0 = rowBase + m * 16 + (lane >> 4) * 4;
#pragma unroll
    for (int n = 0; n < NF; n++) {
      int col = colBase + n * 16 + lr;
      float bs = bias ? bias[col] : 0.f;
#pragma unroll
      for (int j = 0; j < 4; j++) {
        int row = row0 + j;
        long idx = cb + (long)row * ldc + col;
        float v = acc[m][n][j];
        if (EPI == 0) {
          ((u16*)Cp)[idx] = f2bf(v + bs);
        } else if (EPI == 1) {
          ((float*)Cp)[idx] = v + bs + resid[idx];
        } else if (EPI == 2) {
          v += bs;
          float x2 = v * v;
          float e = __expf(v * fmaf(-0.0713548755f, x2, -1.5957691216f));
          v = v * __builtin_amdgcn_rcpf(1.0f + e);
          lmax = fmaxf(fmaxf(lmax, v), 0.0f - v);
          ((u16*)Cp)[idx] = f2bf(v);
        } else if (EPI == 3) {
          ((float*)Cp)[idx] = v + bs + resid[idx];
        }
      }
    }
  }
  if (EPI == 2) {
    __shared__ float redm[4];
    float wm = wredMax(lmax);
    if (lane == 0) redm[wid] = wm;
    __syncthreads();
    if (tid == 0) {
      float bm = fmaxf(fmaxf(redm[0], redm[1]), fmaxf(redm[2], redm[3]));
      condAtomicMax(amax, bm);
    }
  }
}

// ---------------- host ----------------
extern "C" void kernel_launch(void* const* d_in, const int* in_sizes, int n_in,
                              void* d_out, int out_size, void* d_ws, size_t ws_size,
                              hipStream_t stream) {
  const float* hidden = (const float*)d_in[0];
  const float* mask = (const float*)d_in[1];
  const float* ln1g = (const float*)d_in[2];
  const float* ln1b = (const float*)d_in[3];
  const float* ln2g = (const float*)d_in[4];
  const float* ln2b = (const float*)d_in[5];
  const float* w_qkv = (const float*)d_in[6];
  const float* b_qkv = (const float*)d_in[7];
  const float* w_out = (const float*)d_in[8];
  const float* b_out = (const float*)d_in[9];
  const float* w1 = (const float*)d_in[10];
  const float* b1 = (const float*)d_in[11];
  const float* w2 = (const float*)d_in[12];
  const float* b2 = (const float*)d_in[13];

  char* ws = (char*)d_ws;
  u32* sc = (u32*)ws;  // [0]wqkv [1]wout [2]w1 [3]w2 [4]x1 [5]O [6]x2 [7]y1
  u16* wq_qkv = (u16*)(ws + 256);
  u16* wq_out = (u16*)(ws + 6291712);
  u16* wq_w1 = (u16*)(ws + 8388864);
  u16* wq_w2 = (u16*)(ws + 16777472);
  u16* x1 = (u16*)(ws + 25166080);       // LN output, bf16 (also x2)
  u16* xq = (u16*)(ws + 41943296);       // also x2q
  u16* qkv = (u16*)(ws + 50331904);
  u16* S = (u16*)(ws + 75497728);        // y1 (raw+quant)
  u16* O = (u16*)(ws + 142606592);
  float* hbuf = (float*)(ws + 150995200);

  k_init<<<1, 64, 0, stream>>>(sc);

  // weight fake-quant (merged: 2 launches)
  k_absmax4<<<512, 256, 0, stream>>>(
      w_qkv, 3 * C_ * C_ / 4, w_out, C_ * C_ / 4, w1, I_ * C_ / 4, w2, C_ * I_ / 4, sc);
  k_quant4<<<512, 256, 0, stream>>>(
      w_qkv, wq_qkv, 3 * C_ * C_ / 4, w_out, wq_out, C_ * C_ / 4,
      w1, wq_w1, I_ * C_ / 4, w2, wq_w2, C_ * I_ / 4, sc);

  // LN1 (bf16 out) + fq(x)
  k_ln<<<BT, 256, 0, stream>>>(hidden, ln1g, ln1b, x1, sc + 4);
  k_quant_b<<<512, 256, 0, stream>>>(x1, xq, BT * C_ / 8, sc + 4);

  // qkv = xq @ wq_qkv^T + b  -> bf16 [4096,3072]
  k_gemm<128, 128, 0, true><<<dim3(24, 32, 1), 256, 0, stream>>>(
      xq, C_, 0, 0, wq_qkv, C_, 0, 0, b_qkv, qkv, 3 * C_, 0, 0,
      BT, 3 * C_, C_, 1, nullptr, nullptr, nullptr, 0.f);

  // fused attention: scores+softmax+PV -> O [4096,1024] (b,t,h*64+d), + absmax
  k_attn<<<dim3(NH, 2), 256, 0, stream>>>(qkv, mask, O, sc + 5);

  k_quant_bf16<<<512, 256, 0, stream>>>(O, BT * C_ / 8, sc + 5);

  // h = hidden + Oq @ wq_out^T + b  -> f32
  k_gemm<64, 128, 1, true><<<dim3(8, 64, 1), 256, 0, stream>>>(
      O, C_, 0, 0, wq_out, C_, 0, 0, b_out, hbuf, C_, 0, 0,
      BT, C_, C_, 1, hidden, nullptr, nullptr, 0.f);

  // LN2 (bf16 out) + fq
  k_ln<<<BT, 256, 0, stream>>>(hbuf, ln2g, ln2b, x1, sc + 6);
  k_quant_b<<<512, 256, 0, stream>>>(x1, xq, BT * C_ / 8, sc + 6);

  // y1 = gelu(xq @ wq_w1^T + b1) -> bf16 [4096,4096], + absmax
  k_gemm<128, 128, 2, true><<<dim3(32, 32, 1), 256, 0, stream>>>(
      xq, C_, 0, 0, wq_w1, C_, 0, 0, b1, S, I_, 0, 0,
      BT, I_, C_, 1, nullptr, sc + 7, nullptr, 0.f);

  k_quant_bf16<<<512, 256, 0, stream>>>(S, BT * I_ / 8, sc + 7);

  // out = h + y1q @ wq_w2^T + b2 -> f32 d_out
  k_gemm<64, 128, 3, true><<<dim3(8, 64, 1), 256, 0, stream>>>(
      S, I_, 0, 0, wq_w2, I_, 0, 0, b2, d_out, C_, 0, 0,
      BT, C_, I_, 1, hbuf, nullptr, nullptr, 0.f);
}

// Round 12
// 264.915 us; speedup vs baseline: 1.4309x; 1.2806x over previous
//
#include <hip/hip_runtime.h>

typedef __attribute__((ext_vector_type(8))) short bf16x8;
typedef __attribute__((ext_vector_type(4))) float f32x4;
typedef __attribute__((ext_vector_type(4))) int i32x4;
typedef unsigned short u16;
typedef unsigned int u32;

#define B_ 8
#define T_ 512
#define C_ 1024
#define I_ 4096
#define H_ 16
#define Dh_ 64
#define BT (B_*T_)
#define NH (B_*H_)

// ---------------- helpers ----------------
__device__ __forceinline__ float bf2f(u16 u) {
  return __uint_as_float(((u32)u) << 16);
}
__device__ __forceinline__ u16 f2bf(float f) {
  u32 u = __float_as_uint(f);
  u32 r = u + 0x7FFFu + ((u >> 16) & 1u);
  return (u16)(r >> 16);
}
__device__ __forceinline__ float wredMax(float v) {
#pragma unroll
  for (int o = 32; o; o >>= 1) v = fmaxf(v, __shfl_xor(v, o));
  return v;
}
__device__ __forceinline__ float wredSum(float v) {
#pragma unroll
  for (int o = 32; o; o >>= 1) v += __shfl_xor(v, o);
  return v;
}
__device__ __forceinline__ void condAtomicMax(u32* amax, float bm) {
  u32 b = __float_as_uint(bm);
  if (b > *(volatile u32*)amax) atomicMax(amax, b);
}
__device__ __forceinline__ void gload16(const void* g, void* l) {
  __builtin_amdgcn_global_load_lds((const __attribute__((address_space(1))) void*)g,
                                   (__attribute__((address_space(3))) void*)l, 16, 0, 0);
}
// quantize one float to int in [-127,127]
__device__ __forceinline__ int qi(float v, float inv) {
  return (int)fminf(fmaxf(rintf(v * inv), -127.f), 127.f);
}

// ---------------- small kernels ----------------
__global__ void k_init(u32* s) { if (threadIdx.x < 16) s[threadIdx.x] = 0u; }

// absmax of 4 independent f32 arrays -> amax[0..3]
__global__ __launch_bounds__(256) void k_absmax4(
    const float* __restrict__ p0, int n0,
    const float* __restrict__ p1, int n1,
    const float* __restrict__ p2, int n2,
    const float* __restrict__ p3, int n3,
    u32* __restrict__ amax) {
  int stride = gridDim.x * blockDim.x;
  int gid = blockIdx.x * blockDim.x + threadIdx.x;
  float m0 = 0.f, m1 = 0.f, m2 = 0.f, m3 = 0.f;
  for (int i = gid; i < n0; i += stride) {
    float4 v = ((const float4*)p0)[i];
    m0 = fmaxf(m0, fmaxf(fmaxf(fabsf(v.x), fabsf(v.y)), fmaxf(fabsf(v.z), fabsf(v.w))));
  }
  for (int i = gid; i < n1; i += stride) {
    float4 v = ((const float4*)p1)[i];
    m1 = fmaxf(m1, fmaxf(fmaxf(fabsf(v.x), fabsf(v.y)), fmaxf(fabsf(v.z), fabsf(v.w))));
  }
  for (int i = gid; i < n2; i += stride) {
    float4 v = ((const float4*)p2)[i];
    m2 = fmaxf(m2, fmaxf(fmaxf(fabsf(v.x), fabsf(v.y)), fmaxf(fabsf(v.z), fabsf(v.w))));
  }
  for (int i = gid; i < n3; i += stride) {
    float4 v = ((const float4*)p3)[i];
    m3 = fmaxf(m3, fmaxf(fmaxf(fabsf(v.x), fabsf(v.y)), fmaxf(fabsf(v.z), fabsf(v.w))));
  }
  m0 = wredMax(m0); m1 = wredMax(m1); m2 = wredMax(m2); m3 = wredMax(m3);
  __shared__ float red[4][4];
  int wid = threadIdx.x >> 6, lane = threadIdx.x & 63;
  if (lane == 0) { red[wid][0] = m0; red[wid][1] = m1; red[wid][2] = m2; red[wid][3] = m3; }
  __syncthreads();
  if (threadIdx.x < 4) {
    int j = threadIdx.x;
    float bm = fmaxf(fmaxf(red[0][j], red[1][j]), fmaxf(red[2][j], red[3][j]));
    condAtomicMax(amax + j, bm);
  }
}

// quantize 4 independent f32 arrays -> packed int8, scales from amax[0..3]
__global__ __launch_bounds__(256) void k_quant4(
    const float* __restrict__ p0, signed char* __restrict__ q0, int n0,
    const float* __restrict__ p1, signed char* __restrict__ q1, int n1,
    const float* __restrict__ p2, signed char* __restrict__ q2, int n2,
    const float* __restrict__ p3, signed char* __restrict__ q3, int n3,
    const u32* __restrict__ amax) {
  int stride = gridDim.x * blockDim.x;
  int gid = blockIdx.x * blockDim.x + threadIdx.x;
#define QLOOP(p, q, n, slot)                                                        \
  {                                                                                 \
    float s = fmaxf(__uint_as_float(amax[slot]) * (1.0f / 127.0f), 1e-8f);          \
    float inv = 1.0f / s;                                                           \
    for (int i = gid; i < n; i += stride) {                                         \
      float4 v = ((const float4*)p)[i];                                             \
      u32 pk = (u32)(qi(v.x, inv) & 255) | ((u32)(qi(v.y, inv) & 255) << 8) |       \
               ((u32)(qi(v.z, inv) & 255) << 16) | ((u32)(qi(v.w, inv) & 255) << 24); \
      ((u32*)q)[i] = pk;                                                            \
    }                                                                               \
  }
  QLOOP(p0, q0, n0, 0)
  QLOOP(p1, q1, n1, 1)
  QLOOP(p2, q2, n2, 2)
  QLOOP(p3, q3, n3, 3)
#undef QLOOP
}

// quantize bf16 src -> packed int8 dst
__global__ __launch_bounds__(256) void k_quant_b8(const u16* __restrict__ x, signed char* __restrict__ q,
                                                  int n8, const u32* __restrict__ amax) {
  float s = fmaxf(__uint_as_float(*amax) * (1.0f / 127.0f), 1e-8f);
  float inv = 1.0f / s;
  int stride = gridDim.x * blockDim.x;
  for (int i = blockIdx.x * blockDim.x + threadIdx.x; i < n8; i += stride) {
    uint4 d = ((const uint4*)x)[i];
    u16* e = (u16*)&d;
    uint2 o;
    o.x = (u32)(qi(bf2f(e[0]), inv) & 255) | ((u32)(qi(bf2f(e[1]), inv) & 255) << 8) |
          ((u32)(qi(bf2f(e[2]), inv) & 255) << 16) | ((u32)(qi(bf2f(e[3]), inv) & 255) << 24);
    o.y = (u32)(qi(bf2f(e[4]), inv) & 255) | ((u32)(qi(bf2f(e[5]), inv) & 255) << 8) |
          ((u32)(qi(bf2f(e[6]), inv) & 255) << 16) | ((u32)(qi(bf2f(e[7]), inv) & 255) << 24);
    ((uint2*)q)[i] = o;
  }
}

// LayerNorm row (C=1024) -> bf16 out + global absmax (block-reduced)
__global__ __launch_bounds__(256) void k_ln(const float* __restrict__ x, const float* __restrict__ g,
                                            const float* __restrict__ b, u16* __restrict__ y,
                                            u32* __restrict__ amax) {
  int row = blockIdx.x;
  int t = threadIdx.x;
  float4 v = ((const float4*)(x + (long)row * C_))[t];
  float s1 = v.x + v.y + v.z + v.w;
  float s2 = v.x * v.x + v.y * v.y + v.z * v.z + v.w * v.w;
  s1 = wredSum(s1);
  s2 = wredSum(s2);
  __shared__ float red[8];
  int wid = t >> 6, lane = t & 63;
  if (lane == 0) { red[wid] = s1; red[4 + wid] = s2; }
  __syncthreads();
  s1 = red[0] + red[1] + red[2] + red[3];
  s2 = red[4] + red[5] + red[6] + red[7];
  float mean = s1 * (1.0f / C_);
  float var = s2 * (1.0f / C_) - mean * mean;
  float inv = rsqrtf(var + 1e-5f);
  float4 gv = ((const float4*)g)[t];
  float4 bv = ((const float4*)b)[t];
  float4 o;
  o.x = (v.x - mean) * inv * gv.x + bv.x;
  o.y = (v.y - mean) * inv * gv.y + bv.y;
  o.z = (v.z - mean) * inv * gv.z + bv.z;
  o.w = (v.w - mean) * inv * gv.w + bv.w;
  ushort4 ob;
  ob.x = f2bf(o.x); ob.y = f2bf(o.y); ob.z = f2bf(o.z); ob.w = f2bf(o.w);
  ((ushort4*)(y + (long)row * C_))[t] = ob;
  float m = fmaxf(fmaxf(fabsf(o.x), fabsf(o.y)), fmaxf(fabsf(o.z), fabsf(o.w)));
  m = wredMax(m);
  __syncthreads();
  if (lane == 0) red[wid] = m;
  __syncthreads();
  if (t == 0) {
    float bm = fmaxf(fmaxf(red[0], red[1]), fmaxf(red[2], red[3]));
    condAtomicMax(amax, bm);
  }
}

// ---------------- fused attention (unchanged from round 11) ----------------
__global__ __launch_bounds__(256, 1) void k_attn(
    const u16* __restrict__ qkv, const float* __restrict__ mask,
    u16* __restrict__ O, u32* __restrict__ amax) {
  __shared__ u16 Ke[512 * 64];
  __shared__ u16 Vt[64 * 512];
  __shared__ u16 Pl[4 * 64 * 40];
  __shared__ float extl[512];
  __shared__ float redm[4];
  const int tid = threadIdx.x;
  const int w = tid >> 6, l = tid & 63;
  const int head = blockIdx.x;
  const int chunk = blockIdx.y;
  const int b = head >> 4, h = head & 15;
  const long rowbase = (long)(b * 512) * (3 * C_);

  {
    const u16* Kg = qkv + rowbase + C_ + h * 64;
    int lr8 = l >> 3;
    int ls = (l & 7) ^ lr8;
    const long koff = (long)lr8 * (3 * C_) + ls * 8;
#pragma unroll
    for (int i = 0; i < 16; ++i) {
      int r0 = w * 128 + i * 8;
      gload16(Kg + (long)r0 * (3 * C_) + koff, &Ke[r0 * 64]);
    }
  }
  {
    const u16* Vg = qkv + rowbase + 2 * C_ + h * 64;
    int kvl = tid & 31;
    int d0 = (tid >> 5) * 8;
#pragma unroll 4
    for (int i = 0; i < 16; ++i) {
      int kv = i * 32 + kvl;
      uint4 t4 = *(const uint4*)(Vg + (long)kv * (3 * C_) + d0);
      u16* tv = (u16*)&t4;
      int slot = kv >> 3, within = kv & 7;
#pragma unroll
      for (int j = 0; j < 8; ++j) {
        int d = d0 + j;
        Vt[d * 512 + ((slot ^ (d & 7)) << 3) + within] = tv[j];
      }
    }
  }
  {
    const float* mb = mask + b * 512;
    extl[tid] = (1.0f - mb[tid]) * -10000.0f;
    extl[tid + 256] = (1.0f - mb[tid + 256]) * -10000.0f;
  }
  const int qbase = chunk * 256 + w * 64;
  bf16x8 qf[4][2];
  {
    const u16* Qg = qkv + rowbase + h * 64;
#pragma unroll
    for (int qt = 0; qt < 4; ++qt)
#pragma unroll
      for (int dc = 0; dc < 2; ++dc)
        qf[qt][dc] = *(const bf16x8*)(Qg + (long)(qbase + qt * 16 + (l & 15)) * (3 * C_) + dc * 32 + (l >> 4) * 8);
  }
  __syncthreads();

  f32x4 oacc[4][4];
  float mrun[4], lrun[4];
#pragma unroll
  for (int qt = 0; qt < 4; ++qt) { mrun[qt] = -3.0e38f; lrun[qt] = 0.f; }
#pragma unroll
  for (int dt = 0; dt < 4; ++dt)
#pragma unroll
    for (int qt = 0; qt < 4; ++qt) oacc[dt][qt] = (f32x4){0.f, 0.f, 0.f, 0.f};

  u16* Pw = &Pl[w * 64 * 40];

  for (int ks = 0; ks < 16; ++ks) {
    bf16x8 kf[2][2];
#pragma unroll
    for (int kvt = 0; kvt < 2; ++kvt) {
      int kv = ks * 32 + kvt * 16 + (l & 15);
#pragma unroll
      for (int dc = 0; dc < 2; ++dc) {
        int phys = (dc * 4 + (l >> 4)) ^ (kv & 7);
        kf[kvt][dc] = *(const bf16x8*)&Ke[kv * 64 + phys * 8];
      }
    }
    f32x4 sacc[2][4];
#pragma unroll
    for (int kvt = 0; kvt < 2; ++kvt)
#pragma unroll
      for (int qt = 0; qt < 4; ++qt) {
        f32x4 a = (f32x4){0.f, 0.f, 0.f, 0.f};
        a = __builtin_amdgcn_mfma_f32_16x16x32_bf16(kf[kvt][0], qf[qt][0], a, 0, 0, 0);
        a = __builtin_amdgcn_mfma_f32_16x16x32_bf16(kf[kvt][1], qf[qt][1], a, 0, 0, 0);
        sacc[kvt][qt] = a;
      }
#pragma unroll
    for (int kvt = 0; kvt < 2; ++kvt) {
      f32x4 ev = *(const f32x4*)&extl[ks * 32 + kvt * 16 + (l >> 4) * 4];
#pragma unroll
      for (int qt = 0; qt < 4; ++qt)
#pragma unroll
        for (int r = 0; r < 4; ++r)
          sacc[kvt][qt][r] = fmaf(sacc[kvt][qt][r], 0.125f, ev[r]);
    }
#pragma unroll
    for (int qt = 0; qt < 4; ++qt) {
      float pm = sacc[0][qt][0];
#pragma unroll
      for (int r = 1; r < 4; ++r) pm = fmaxf(pm, sacc[0][qt][r]);
#pragma unroll
      for (int r = 0; r < 4; ++r) pm = fmaxf(pm, sacc[1][qt][r]);
      pm = fmaxf(pm, __shfl_xor(pm, 16));
      pm = fmaxf(pm, __shfl_xor(pm, 32));
      float mnew = fmaxf(mrun[qt], pm);
      float f = __expf(mrun[qt] - mnew);
      mrun[qt] = mnew;
      float lsum = 0.f;
#pragma unroll
      for (int kvt = 0; kvt < 2; ++kvt)
#pragma unroll
        for (int r = 0; r < 4; ++r) {
          float p = __expf(sacc[kvt][qt][r] - mnew);
          sacc[kvt][qt][r] = p;
          lsum += p;
        }
      lsum += __shfl_xor(lsum, 16);
      lsum += __shfl_xor(lsum, 32);
      lrun[qt] = lrun[qt] * f + lsum;
#pragma unroll
      for (int dt = 0; dt < 4; ++dt)
#pragma unroll
        for (int r = 0; r < 4; ++r) oacc[dt][qt][r] *= f;
#pragma unroll
      for (int kvt = 0; kvt < 2; ++kvt) {
        u32 p01 = (u32)f2bf(sacc[kvt][qt][0]) | ((u32)f2bf(sacc[kvt][qt][1]) << 16);
        u32 p23 = (u32)f2bf(sacc[kvt][qt][2]) | ((u32)f2bf(sacc[kvt][qt][3]) << 16);
        u16* pr = Pw + (qt * 16 + (l & 15)) * 40 + kvt * 16 + (l >> 4) * 4;
        *(u32*)pr = p01;
        *(u32*)(pr + 2) = p23;
      }
    }
    bf16x8 vf[4], pf[4];
#pragma unroll
    for (int dt = 0; dt < 4; ++dt) {
      int d = dt * 16 + (l & 15);
      int phys = (ks * 4 + (l >> 4)) ^ (d & 7);
      vf[dt] = *(const bf16x8*)&Vt[d * 512 + phys * 8];
    }
#pragma unroll
    for (int qt = 0; qt < 4; ++qt)
      pf[qt] = *(const bf16x8*)(Pw + (qt * 16 + (l & 15)) * 40 + (l >> 4) * 8);
#pragma unroll
    for (int dt = 0; dt < 4; ++dt)
#pragma unroll
      for (int qt = 0; qt < 4; ++qt)
        oacc[dt][qt] = __builtin_amdgcn_mfma_f32_16x16x32_bf16(vf[dt], pf[qt], oacc[dt][qt], 0, 0, 0);
  }

  float lmax = 0.f;
  u16* Ob = O + (long)(b * 512 + qbase) * C_ + h * 64;
#pragma unroll
  for (int qt = 0; qt < 4; ++qt) {
    float inv = 1.0f / lrun[qt];
    long qoff = (long)(qt * 16 + (l & 15)) * C_;
#pragma unroll
    for (int dt = 0; dt < 4; ++dt) {
      int d = dt * 16 + (l >> 4) * 4;
      float v0 = oacc[dt][qt][0] * inv;
      float v1 = oacc[dt][qt][1] * inv;
      float v2 = oacc[dt][qt][2] * inv;
      float v3 = oacc[dt][qt][3] * inv;
      lmax = fmaxf(fmaxf(lmax, fmaxf(fabsf(v0), fabsf(v1))), fmaxf(fabsf(v2), fabsf(v3)));
      u32 a01 = (u32)f2bf(v0) | ((u32)f2bf(v1) << 16);
      u32 a23 = (u32)f2bf(v2) | ((u32)f2bf(v3) << 16);
      *(u32*)(Ob + qoff + d) = a01;
      *(u32*)(Ob + qoff + d + 2) = a23;
    }
  }
  lmax = wredMax(lmax);
  if (l == 0) redm[w] = lmax;
  __syncthreads();
  if (tid == 0)
    condAtomicMax(amax, fmaxf(fmaxf(redm[0], redm[1]), fmaxf(redm[2], redm[3])));
}

// ---------------- int8 MFMA GEMM ----------------
// C[M,N] = (A_i8[M,K] * B_i8[N,K]^T) * sA*sB + epilogue.  BK=128 (128B rows,
// 8x16B slots, XOR slot-swizzle phys = slot ^ (row&7)); global_load_lds with
// pre-swizzled per-lane source; double-buffered counted-vmcnt pipeline (T3+T4).
// EPI: 0 = +bias -> bf16 | 1 = +bias+resid -> f32 | 2 = +bias,gelu,absmax -> bf16
//      3 = +bias+resid -> f32 (final)
template <int BM, int BN, int EPI, bool SWZ>
__global__ __launch_bounds__(256) void k_gemmq(
    const signed char* __restrict__ A, int lda,
    const signed char* __restrict__ Bm, int ldb,
    const float* __restrict__ bias,
    void* __restrict__ Cp, int ldc,
    int M, int N, int K,
    const float* __restrict__ resid,
    u32* __restrict__ amaxOut,
    const u32* __restrict__ amaxA, const u32* __restrict__ amaxB) {
  constexpr int BK = 128;
  constexpr int MF = (BM / 2) / 16;
  constexpr int NF = (BN / 2) / 16;
  __shared__ __align__(16) signed char As[2][BM * BK];
  __shared__ __align__(16) signed char Bs[2][BN * BK];
  const int tid = threadIdx.x;
  const int wid = tid >> 6, lane = tid & 63;
  const int wr = wid >> 1, wc = wid & 1;

  float sa = fmaxf(__uint_as_float(*amaxA) * (1.0f / 127.0f), 1e-8f);
  float sb = fmaxf(__uint_as_float(*amaxB) * (1.0f / 127.0f), 1e-8f);
  const float sAB = sa * sb;

  int bx = blockIdx.x, by = blockIdx.y;
  if (SWZ) {
    int gx = gridDim.x;
    int nwg = gx * gridDim.y;       // all SWZ call sites have nwg % 8 == 0
    int bid = by * gx + bx;
    int cpx = nwg >> 3;
    int swz = (bid & 7) * cpx + (bid >> 3);
    bx = swz % gx;
    by = swz / gx;
  }

  const signed char* Ab = A + (long)by * BM * lda;
  const signed char* Bb = Bm + (long)bx * BN * ldb;

  i32x4 acc[MF][NF];
#pragma unroll
  for (int m = 0; m < MF; m++)
#pragma unroll
    for (int n = 0; n < NF; n++) acc[m][n] = (i32x4){0, 0, 0, 0};

  const int lr = lane & 15;
  const int l8 = lane >> 3;              // row within 8-row stripe
  const int s8 = (lane & 7) ^ l8;        // swizzled 16B slot to fetch
  const long aoff = (long)l8 * lda + s8 * 16;
  const long boff = (long)l8 * ldb + s8 * 16;

  auto stageAB = [&](int buf, int k0) {
#pragma unroll
    for (int i = 0; i < BM / 32; ++i) {
      int R0 = wid * (BM / 4) + i * 8;
      gload16(Ab + (long)R0 * lda + k0 + aoff, &As[buf][R0 * BK]);
    }
#pragma unroll
    for (int i = 0; i < BN / 32; ++i) {
      int R0 = wid * (BN / 4) + i * 8;
      gload16(Bb + (long)R0 * ldb + k0 + boff, &Bs[buf][R0 * BK]);
    }
  };

  auto waitCounted = [&]() {
    if constexpr ((BM / 32 + BN / 32) == 8) {
      asm volatile("s_waitcnt vmcnt(8)" ::: "memory");
    } else {
      asm volatile("s_waitcnt vmcnt(6)" ::: "memory");
    }
  };

  auto computeK = [&](int buf) {
#pragma unroll
    for (int kk = 0; kk < 2; ++kk) {
      const int sl = (kk << 2) + (lane >> 4);       // 16B slot (K=64 chunk)
      const int sf = (sl ^ (lr & 7)) << 4;          // swizzled byte offset
      i32x4 af[MF], bfr[NF];
#pragma unroll
      for (int m = 0; m < MF; m++)
        af[m] = *(const i32x4*)&As[buf][(wr * (BM / 2) + m * 16 + lr) * BK + sf];
#pragma unroll
      for (int n = 0; n < NF; n++)
        bfr[n] = *(const i32x4*)&Bs[buf][(wc * (BN / 2) + n * 16 + lr) * BK + sf];
      __builtin_amdgcn_s_setprio(1);
#pragma unroll
      for (int m = 0; m < MF; m++)
#pragma unroll
        for (int n = 0; n < NF; n++)
          acc[m][n] = __builtin_amdgcn_mfma_i32_16x16x64_i8(af[m], bfr[n], acc[m][n], 0, 0, 0);
      __builtin_amdgcn_s_setprio(0);
    }
  };

  const int nt = K / BK;
  stageAB(0, 0);
  int cur = 0;
  for (int t = 0; t < nt; ++t) {
    if (t + 1 < nt) {
      stageAB(cur ^ 1, (t + 1) * BK);
      waitCounted();
    } else {
      asm volatile("s_waitcnt vmcnt(0)" ::: "memory");
    }
    __builtin_amdgcn_s_barrier();
    computeK(cur);
    if (t + 1 < nt)
      __builtin_amdgcn_s_barrier();
    cur ^= 1;
  }

  const int rowBase = by * BM + wr * (BM / 2);
  const int colBase = bx * BN + wc * (BN / 2);
  float lmax = 0.f;
#pragma unroll
  for (int m = 0; m < MF; m++) {
    int row0 = rowBase + m * 16 + (lane >> 4) * 4;
#pragma unroll
    for (int n = 0; n < NF; n++) {
      int col = colBase + n * 16 + lr;
      float bs = bias[col];
#pragma unroll
      for (int j = 0; j < 4; j++) {
        int row = row0 + j;
        long idx = (long)row * ldc + col;
        float v = (float)acc[m][n][j] * sAB;
        if (EPI == 0) {
          ((u16*)Cp)[idx] = f2bf(v + bs);
        } else if (EPI == 1) {
          ((float*)Cp)[idx] = v + bs + resid[idx];
        } else if (EPI == 2) {
          v += bs;
          float x2 = v * v;
          float e = __expf(v * fmaf(-0.0713548755f, x2, -1.5957691216f));
          v = v * __builtin_amdgcn_rcpf(1.0f + e);
          lmax = fmaxf(fmaxf(lmax, v), 0.0f - v);
          ((u16*)Cp)[idx] = f2bf(v);
        } else if (EPI == 3) {
          ((float*)Cp)[idx] = v + bs + resid[idx];
        }
      }
    }
  }
  if (EPI == 2) {
    __shared__ float redm[4];
    float wm = wredMax(lmax);
    if (lane == 0) redm[wid] = wm;
    __syncthreads();
    if (tid == 0) {
      float bm = fmaxf(fmaxf(redm[0], redm[1]), fmaxf(redm[2], redm[3]));
      condAtomicMax(amaxOut, bm);
    }
  }
}

// ---------------- host ----------------
extern "C" void kernel_launch(void* const* d_in, const int* in_sizes, int n_in,
                              void* d_out, int out_size, void* d_ws, size_t ws_size,
                              hipStream_t stream) {
  const float* hidden = (const float*)d_in[0];
  const float* mask = (const float*)d_in[1];
  const float* ln1g = (const float*)d_in[2];
  const float* ln1b = (const float*)d_in[3];
  const float* ln2g = (const float*)d_in[4];
  const float* ln2b = (const float*)d_in[5];
  const float* w_qkv = (const float*)d_in[6];
  const float* b_qkv = (const float*)d_in[7];
  const float* w_out = (const float*)d_in[8];
  const float* b_out = (const float*)d_in[9];
  const float* w1 = (const float*)d_in[10];
  const float* b1 = (const float*)d_in[11];
  const float* w2 = (const float*)d_in[12];
  const float* b2 = (const float*)d_in[13];

  char* ws = (char*)d_ws;
  u32* sc = (u32*)ws;  // [0]wqkv [1]wout [2]w1 [3]w2 [4]x1 [5]O [6]x2 [7]y1
  const long MB = 1024 * 1024;
  signed char* wq_qkv = (signed char*)(ws + 1 * MB);    // 3 MB
  signed char* wq_out = (signed char*)(ws + 4 * MB);    // 1 MB
  signed char* wq_w1  = (signed char*)(ws + 6 * MB);    // 4 MB
  signed char* wq_w2  = (signed char*)(ws + 10 * MB);   // 4 MB
  signed char* xq     = (signed char*)(ws + 14 * MB);   // 4 MB (x1q / x2q)
  u16* x1             = (u16*)(ws + 18 * MB);           // 8 MB (LN out bf16)
  signed char* Oq     = (signed char*)(ws + 26 * MB);   // 4 MB
  u16* O              = (u16*)(ws + 30 * MB);           // 8 MB
  u16* qkv            = (u16*)(ws + 38 * MB);           // 24 MB
  float* hbuf         = (float*)(ws + 62 * MB);         // 16 MB
  u16* y1             = (u16*)(ws + 78 * MB);           // 32 MB
  signed char* y1q    = (signed char*)(ws + 110 * MB);  // 16 MB
  // total 126 MB

  k_init<<<1, 64, 0, stream>>>(sc);

  // weight absmax + int8 quant (2 launches)
  k_absmax4<<<512, 256, 0, stream>>>(
      w_qkv, 3 * C_ * C_ / 4, w_out, C_ * C_ / 4, w1, I_ * C_ / 4, w2, C_ * I_ / 4, sc);
  k_quant4<<<512, 256, 0, stream>>>(
      w_qkv, wq_qkv, 3 * C_ * C_ / 4, w_out, wq_out, C_ * C_ / 4,
      w1, wq_w1, I_ * C_ / 4, w2, wq_w2, C_ * I_ / 4, sc);

  // LN1 -> bf16 + amax; quantize to int8
  k_ln<<<BT, 256, 0, stream>>>(hidden, ln1g, ln1b, x1, sc + 4);
  k_quant_b8<<<512, 256, 0, stream>>>(x1, xq, BT * C_ / 8, sc + 4);

  // qkv = (xq . wq_qkv^T)*s + b -> bf16 [4096,3072]
  k_gemmq<128, 128, 0, true><<<dim3(24, 32), 256, 0, stream>>>(
      xq, C_, wq_qkv, C_, b_qkv, qkv, 3 * C_,
      BT, 3 * C_, C_, nullptr, nullptr, sc + 4, sc + 0);

  // fused attention -> O bf16 [4096,1024] (b,t,h*64+d), + amax
  k_attn<<<dim3(NH, 2), 256, 0, stream>>>(qkv, mask, O, sc + 5);
  k_quant_b8<<<512, 256, 0, stream>>>(O, Oq, BT * C_ / 8, sc + 5);

  // h = hidden + (Oq . wq_out^T)*s + b -> f32
  k_gemmq<64, 128, 1, true><<<dim3(8, 64), 256, 0, stream>>>(
      Oq, C_, wq_out, C_, b_out, hbuf, C_,
      BT, C_, C_, hidden, nullptr, sc + 5, sc + 1);

  // LN2 -> bf16 + amax; quantize
  k_ln<<<BT, 256, 0, stream>>>(hbuf, ln2g, ln2b, x1, sc + 6);
  k_quant_b8<<<512, 256, 0, stream>>>(x1, xq, BT * C_ / 8, sc + 6);

  // y1 = gelu((xq . wq_w1^T)*s + b1) -> bf16 [4096,4096], + amax
  k_gemmq<128, 128, 2, true><<<dim3(32, 32), 256, 0, stream>>>(
      xq, C_, wq_w1, C_, b1, y1, I_,
      BT, I_, C_, nullptr, sc + 7, sc + 6, sc + 2);
  k_quant_b8<<<512, 256, 0, stream>>>(y1, y1q, BT * I_ / 8, sc + 7);

  // out = h + (y1q . wq_w2^T)*s + b2 -> f32 d_out
  k_gemmq<64, 128, 3, true><<<dim3(8, 64), 256, 0, stream>>>(
      y1q, I_, wq_w2, I_, b2, d_out, C_,
      BT, C_, I_, hbuf, nullptr, sc + 7, sc + 3);
}

// Round 14
// 251.178 us; speedup vs baseline: 1.5092x; 1.0547x over previous
//
#include <hip/hip_runtime.h>

typedef __attribute__((ext_vector_type(8))) short bf16x8;
typedef __attribute__((ext_vector_type(4))) float f32x4;
typedef __attribute__((ext_vector_type(4))) int i32x4;
typedef unsigned short u16;
typedef unsigned int u32;

#define B_ 8
#define T_ 512
#define C_ 1024
#define I_ 4096
#define H_ 16
#define Dh_ 64
#define BT (B_*T_)
#define NH (B_*H_)

// ---------------- helpers ----------------
__device__ __forceinline__ float bf2f(u16 u) {
  return __uint_as_float(((u32)u) << 16);
}
__device__ __forceinline__ u16 f2bf(float f) {
  u32 u = __float_as_uint(f);
  u32 r = u + 0x7FFFu + ((u >> 16) & 1u);
  return (u16)(r >> 16);
}
__device__ __forceinline__ float wredMax(float v) {
#pragma unroll
  for (int o = 32; o; o >>= 1) v = fmaxf(v, __shfl_xor(v, o));
  return v;
}
__device__ __forceinline__ float wredSum(float v) {
#pragma unroll
  for (int o = 32; o; o >>= 1) v += __shfl_xor(v, o);
  return v;
}
// 64-slot strided max array (one 64B line per slot): producers atomic into
// slot (bid&63); consumers reduce 64 lines.  Monotone + commutative =>
// deterministic.  Spreads RMW serialization across 64 parallel L2 queues.
__device__ __forceinline__ void slotAtomicMax(u32* arr, int bid, float bm) {
  u32 b = __float_as_uint(bm);
  volatile u32* p = arr + ((bid & 63) << 4);
  if (b > *p) atomicMax((u32*)p, b);
}
__device__ __forceinline__ float slotMax(const u32* __restrict__ arr) {
  float m = 0.f;
#pragma unroll
  for (int i = 0; i < 64; ++i) m = fmaxf(m, __uint_as_float(arr[i << 4]));
  return m;
}
__device__ __forceinline__ void gload16(const void* g, void* l) {
  __builtin_amdgcn_global_load_lds((const __attribute__((address_space(1))) void*)g,
                                   (__attribute__((address_space(3))) void*)l, 16, 0, 0);
}
// quantize one float to int in [-127,127]
__device__ __forceinline__ int qi(float v, float inv) {
  return (int)fminf(fmaxf(rintf(v * inv), -127.f), 127.f);
}

// ---------------- small kernels ----------------
// zero all 8 slot-arrays (8 * 64 * 16 u32 = 32 KB)
__global__ void k_init(u32* s) {
  int i = blockIdx.x * 256 + threadIdx.x;
  if (i < 8192) s[i] = 0u;
}

// absmax of 4 independent f32 arrays -> slot arrays 0..3
__global__ __launch_bounds__(256) void k_absmax4(
    const float* __restrict__ p0, int n0,
    const float* __restrict__ p1, int n1,
    const float* __restrict__ p2, int n2,
    const float* __restrict__ p3, int n3,
    u32* __restrict__ sc) {
  int stride = gridDim.x * blockDim.x;
  int gid = blockIdx.x * blockDim.x + threadIdx.x;
  float m0 = 0.f, m1 = 0.f, m2 = 0.f, m3 = 0.f;
  for (int i = gid; i < n0; i += stride) {
    float4 v = ((const float4*)p0)[i];
    m0 = fmaxf(m0, fmaxf(fmaxf(fabsf(v.x), fabsf(v.y)), fmaxf(fabsf(v.z), fabsf(v.w))));
  }
  for (int i = gid; i < n1; i += stride) {
    float4 v = ((const float4*)p1)[i];
    m1 = fmaxf(m1, fmaxf(fmaxf(fabsf(v.x), fabsf(v.y)), fmaxf(fabsf(v.z), fabsf(v.w))));
  }
  for (int i = gid; i < n2; i += stride) {
    float4 v = ((const float4*)p2)[i];
    m2 = fmaxf(m2, fmaxf(fmaxf(fabsf(v.x), fabsf(v.y)), fmaxf(fabsf(v.z), fabsf(v.w))));
  }
  for (int i = gid; i < n3; i += stride) {
    float4 v = ((const float4*)p3)[i];
    m3 = fmaxf(m3, fmaxf(fmaxf(fabsf(v.x), fabsf(v.y)), fmaxf(fabsf(v.z), fabsf(v.w))));
  }
  m0 = wredMax(m0); m1 = wredMax(m1); m2 = wredMax(m2); m3 = wredMax(m3);
  __shared__ float red[4][4];
  int wid = threadIdx.x >> 6, lane = threadIdx.x & 63;
  if (lane == 0) { red[wid][0] = m0; red[wid][1] = m1; red[wid][2] = m2; red[wid][3] = m3; }
  __syncthreads();
  if (threadIdx.x < 4) {
    int j = threadIdx.x;
    float bm = fmaxf(fmaxf(red[0][j], red[1][j]), fmaxf(red[2][j], red[3][j]));
    slotAtomicMax(sc + j * 1024, blockIdx.x, bm);
  }
}

// quantize 4 independent f32 arrays -> packed int8, scales from slot arrays
__global__ __launch_bounds__(256) void k_quant4(
    const float* __restrict__ p0, signed char* __restrict__ q0, int n0,
    const float* __restrict__ p1, signed char* __restrict__ q1, int n1,
    const float* __restrict__ p2, signed char* __restrict__ q2, int n2,
    const float* __restrict__ p3, signed char* __restrict__ q3, int n3,
    const u32* __restrict__ sc) {
  int stride = gridDim.x * blockDim.x;
  int gid = blockIdx.x * blockDim.x + threadIdx.x;
#define QLOOP(p, q, n, slot)                                                        \
  {                                                                                 \
    float s = fmaxf(slotMax(sc + slot * 1024) * (1.0f / 127.0f), 1e-8f);            \
    float inv = 1.0f / s;                                                           \
    for (int i = gid; i < n; i += stride) {                                         \
      float4 v = ((const float4*)p)[i];                                             \
      u32 pk = (u32)(qi(v.x, inv) & 255) | ((u32)(qi(v.y, inv) & 255) << 8) |       \
               ((u32)(qi(v.z, inv) & 255) << 16) | ((u32)(qi(v.w, inv) & 255) << 24); \
      ((u32*)q)[i] = pk;                                                            \
    }                                                                               \
  }
  QLOOP(p0, q0, n0, 0)
  QLOOP(p1, q1, n1, 1)
  QLOOP(p2, q2, n2, 2)
  QLOOP(p3, q3, n3, 3)
#undef QLOOP
}

// quantize bf16 src -> packed int8 dst, scale from slot array
__global__ __launch_bounds__(256) void k_quant_b8(const u16* __restrict__ x, signed char* __restrict__ q,
                                                  int n8, const u32* __restrict__ arr) {
  float s = fmaxf(slotMax(arr) * (1.0f / 127.0f), 1e-8f);
  float inv = 1.0f / s;
  int stride = gridDim.x * blockDim.x;
  for (int i = blockIdx.x * blockDim.x + threadIdx.x; i < n8; i += stride) {
    uint4 d = ((const uint4*)x)[i];
    u16* e = (u16*)&d;
    uint2 o;
    o.x = (u32)(qi(bf2f(e[0]), inv) & 255) | ((u32)(qi(bf2f(e[1]), inv) & 255) << 8) |
          ((u32)(qi(bf2f(e[2]), inv) & 255) << 16) | ((u32)(qi(bf2f(e[3]), inv) & 255) << 24);
    o.y = (u32)(qi(bf2f(e[4]), inv) & 255) | ((u32)(qi(bf2f(e[5]), inv) & 255) << 8) |
          ((u32)(qi(bf2f(e[6]), inv) & 255) << 16) | ((u32)(qi(bf2f(e[7]), inv) & 255) << 24);
    ((uint2*)q)[i] = o;
  }
}

// LayerNorm row (C=1024) -> bf16 out + slot absmax
__global__ __launch_bounds__(256) void k_ln(const float* __restrict__ x, const float* __restrict__ g,
                                            const float* __restrict__ b, u16* __restrict__ y,
                                            u32* __restrict__ arr) {
  int row = blockIdx.x;
  int t = threadIdx.x;
  float4 v = ((const float4*)(x + (long)row * C_))[t];
  float s1 = v.x + v.y + v.z + v.w;
  float s2 = v.x * v.x + v.y * v.y + v.z * v.z + v.w * v.w;
  s1 = wredSum(s1);
  s2 = wredSum(s2);
  __shared__ float red[8];
  int wid = t >> 6, lane = t & 63;
  if (lane == 0) { red[wid] = s1; red[4 + wid] = s2; }
  __syncthreads();
  s1 = red[0] + red[1] + red[2] + red[3];
  s2 = red[4] + red[5] + red[6] + red[7];
  float mean = s1 * (1.0f / C_);
  float var = s2 * (1.0f / C_) - mean * mean;
  float inv = rsqrtf(var + 1e-5f);
  float4 gv = ((const float4*)g)[t];
  float4 bv = ((const float4*)b)[t];
  float4 o;
  o.x = (v.x - mean) * inv * gv.x + bv.x;
  o.y = (v.y - mean) * inv * gv.y + bv.y;
  o.z = (v.z - mean) * inv * gv.z + bv.z;
  o.w = (v.w - mean) * inv * gv.w + bv.w;
  ushort4 ob;
  ob.x = f2bf(o.x); ob.y = f2bf(o.y); ob.z = f2bf(o.z); ob.w = f2bf(o.w);
  ((ushort4*)(y + (long)row * C_))[t] = ob;
  float m = fmaxf(fmaxf(fabsf(o.x), fabsf(o.y)), fmaxf(fabsf(o.z), fabsf(o.w)));
  m = wredMax(m);
  __syncthreads();
  if (lane == 0) red[wid] = m;
  __syncthreads();
  if (t == 0) {
    float bm = fmaxf(fmaxf(red[0], red[1]), fmaxf(red[2], red[3]));
    slotAtomicMax(arr, row, bm);
  }
}

// ---------------- fused attention ----------------
__global__ __launch_bounds__(256, 1) void k_attn(
    const u16* __restrict__ qkv, const float* __restrict__ mask,
    u16* __restrict__ O, u32* __restrict__ amax) {
  __shared__ u16 Ke[512 * 64];
  __shared__ u16 Vt[64 * 512];
  __shared__ u16 Pl[4 * 64 * 40];
  __shared__ float extl[512];
  __shared__ float redm[4];
  const int tid = threadIdx.x;
  const int w = tid >> 6, l = tid & 63;
  const int head = blockIdx.x;
  const int chunk = blockIdx.y;
  const int b = head >> 4, h = head & 15;
  const long rowbase = (long)(b * 512) * (3 * C_);

  {
    const u16* Kg = qkv + rowbase + C_ + h * 64;
    int lr8 = l >> 3;
    int ls = (l & 7) ^ lr8;
    const long koff = (long)lr8 * (3 * C_) + ls * 8;
#pragma unroll
    for (int i = 0; i < 16; ++i) {
      int r0 = w * 128 + i * 8;
      gload16(Kg + (long)r0 * (3 * C_) + koff, &Ke[r0 * 64]);
    }
  }
  {
    const u16* Vg = qkv + rowbase + 2 * C_ + h * 64;
    int kvl = tid & 31;
    int d0 = (tid >> 5) * 8;
#pragma unroll 4
    for (int i = 0; i < 16; ++i) {
      int kv = i * 32 + kvl;
      uint4 t4 = *(const uint4*)(Vg + (long)kv * (3 * C_) + d0);
      u16* tv = (u16*)&t4;
      int slot = kv >> 3, within = kv & 7;
#pragma unroll
      for (int j = 0; j < 8; ++j) {
        int d = d0 + j;
        Vt[d * 512 + ((slot ^ (d & 7)) << 3) + within] = tv[j];
      }
    }
  }
  {
    const float* mb = mask + b * 512;
    extl[tid] = (1.0f - mb[tid]) * -10000.0f;
    extl[tid + 256] = (1.0f - mb[tid + 256]) * -10000.0f;
  }
  const int qbase = chunk * 256 + w * 64;
  bf16x8 qf[4][2];
  {
    const u16* Qg = qkv + rowbase + h * 64;
#pragma unroll
    for (int qt = 0; qt < 4; ++qt)
#pragma unroll
      for (int dc = 0; dc < 2; ++dc)
        qf[qt][dc] = *(const bf16x8*)(Qg + (long)(qbase + qt * 16 + (l & 15)) * (3 * C_) + dc * 32 + (l >> 4) * 8);
  }
  __syncthreads();

  f32x4 oacc[4][4];
  float mrun[4], lrun[4];
#pragma unroll
  for (int qt = 0; qt < 4; ++qt) { mrun[qt] = -3.0e38f; lrun[qt] = 0.f; }
#pragma unroll
  for (int dt = 0; dt < 4; ++dt)
#pragma unroll
    for (int qt = 0; qt < 4; ++qt) oacc[dt][qt] = (f32x4){0.f, 0.f, 0.f, 0.f};

  u16* Pw = &Pl[w * 64 * 40];

  for (int ks = 0; ks < 16; ++ks) {
    bf16x8 kf[2][2];
#pragma unroll
    for (int kvt = 0; kvt < 2; ++kvt) {
      int kv = ks * 32 + kvt * 16 + (l & 15);
#pragma unroll
      for (int dc = 0; dc < 2; ++dc) {
        int phys = (dc * 4 + (l >> 4)) ^ (kv & 7);
        kf[kvt][dc] = *(const bf16x8*)&Ke[kv * 64 + phys * 8];
      }
    }
    f32x4 sacc[2][4];
#pragma unroll
    for (int kvt = 0; kvt < 2; ++kvt)
#pragma unroll
      for (int qt = 0; qt < 4; ++qt) {
        f32x4 a = (f32x4){0.f, 0.f, 0.f, 0.f};
        a = __builtin_amdgcn_mfma_f32_16x16x32_bf16(kf[kvt][0], qf[qt][0], a, 0, 0, 0);
        a = __builtin_amdgcn_mfma_f32_16x16x32_bf16(kf[kvt][1], qf[qt][1], a, 0, 0, 0);
        sacc[kvt][qt] = a;
      }
#pragma unroll
    for (int kvt = 0; kvt < 2; ++kvt) {
      f32x4 ev = *(const f32x4*)&extl[ks * 32 + kvt * 16 + (l >> 4) * 4];
#pragma unroll
      for (int qt = 0; qt < 4; ++qt)
#pragma unroll
        for (int r = 0; r < 4; ++r)
          sacc[kvt][qt][r] = fmaf(sacc[kvt][qt][r], 0.125f, ev[r]);
    }
#pragma unroll
    for (int qt = 0; qt < 4; ++qt) {
      float pm = sacc[0][qt][0];
#pragma unroll
      for (int r = 1; r < 4; ++r) pm = fmaxf(pm, sacc[0][qt][r]);
#pragma unroll
      for (int r = 0; r < 4; ++r) pm = fmaxf(pm, sacc[1][qt][r]);
      pm = fmaxf(pm, __shfl_xor(pm, 16));
      pm = fmaxf(pm, __shfl_xor(pm, 32));
      float mnew = fmaxf(mrun[qt], pm);
      float f = __expf(mrun[qt] - mnew);
      mrun[qt] = mnew;
      float lsum = 0.f;
#pragma unroll
      for (int kvt = 0; kvt < 2; ++kvt)
#pragma unroll
        for (int r = 0; r < 4; ++r) {
          float p = __expf(sacc[kvt][qt][r] - mnew);
          sacc[kvt][qt][r] = p;
          lsum += p;
        }
      lsum += __shfl_xor(lsum, 16);
      lsum += __shfl_xor(lsum, 32);
      lrun[qt] = lrun[qt] * f + lsum;
#pragma unroll
      for (int dt = 0; dt < 4; ++dt)
#pragma unroll
        for (int r = 0; r < 4; ++r) oacc[dt][qt][r] *= f;
#pragma unroll
      for (int kvt = 0; kvt < 2; ++kvt) {
        u32 p01 = (u32)f2bf(sacc[kvt][qt][0]) | ((u32)f2bf(sacc[kvt][qt][1]) << 16);
        u32 p23 = (u32)f2bf(sacc[kvt][qt][2]) | ((u32)f2bf(sacc[kvt][qt][3]) << 16);
        u16* pr = Pw + (qt * 16 + (l & 15)) * 40 + kvt * 16 + (l >> 4) * 4;
        *(u32*)pr = p01;
        *(u32*)(pr + 2) = p23;
      }
    }
    bf16x8 vf[4], pf[4];
#pragma unroll
    for (int dt = 0; dt < 4; ++dt) {
      int d = dt * 16 + (l & 15);
      int phys = (ks * 4 + (l >> 4)) ^ (d & 7);
      vf[dt] = *(const bf16x8*)&Vt[d * 512 + phys * 8];
    }
#pragma unroll
    for (int qt = 0; qt < 4; ++qt)
      pf[qt] = *(const bf16x8*)(Pw + (qt * 16 + (l & 15)) * 40 + (l >> 4) * 8);
#pragma unroll
    for (int dt = 0; dt < 4; ++dt)
#pragma unroll
      for (int qt = 0; qt < 4; ++qt)
        oacc[dt][qt] = __builtin_amdgcn_mfma_f32_16x16x32_bf16(vf[dt], pf[qt], oacc[dt][qt], 0, 0, 0);
  }

  float lmax = 0.f;
  u16* Ob = O + (long)(b * 512 + qbase) * C_ + h * 64;
#pragma unroll
  for (int qt = 0; qt < 4; ++qt) {
    float inv = 1.0f / lrun[qt];
    long qoff = (long)(qt * 16 + (l & 15)) * C_;
#pragma unroll
    for (int dt = 0; dt < 4; ++dt) {
      int d = dt * 16 + (l >> 4) * 4;
      float v0 = oacc[dt][qt][0] * inv;
      float v1 = oacc[dt][qt][1] * inv;
      float v2 = oacc[dt][qt][2] * inv;
      float v3 = oacc[dt][qt][3] * inv;
      lmax = fmaxf(fmaxf(lmax, fmaxf(fabsf(v0), fabsf(v1))), fmaxf(fabsf(v2), fabsf(v3)));
      u32 a01 = (u32)f2bf(v0) | ((u32)f2bf(v1) << 16);
      u32 a23 = (u32)f2bf(v2) | ((u32)f2bf(v3) << 16);
      *(u32*)(Ob + qoff + d) = a01;
      *(u32*)(Ob + qoff + d + 2) = a23;
    }
  }
  lmax = wredMax(lmax);
  if (l == 0) redm[w] = lmax;
  __syncthreads();
  if (tid == 0)
    slotAtomicMax(amax, blockIdx.x * 2 + blockIdx.y,
                  fmaxf(fmaxf(redm[0], redm[1]), fmaxf(redm[2], redm[3])));
}

// ---------------- int8 MFMA GEMM ----------------
// C[M,N] = (A_i8[M,K] * B_i8[N,K]^T) * sA*sB + epilogue.  BK=128; XOR
// slot-swizzle; global_load_lds pre-swizzled source; counted-vmcnt dbuf.
// EPI: 0 = +bias -> bf16 | 1 = +bias+resid -> f32 | 2 = +bias,gelu,absmax -> bf16
//      3 = +bias+resid -> f32 (final)
template <int BM, int BN, int EPI, bool SWZ>
__global__ __launch_bounds__(256) void k_gemmq(
    const signed char* __restrict__ A, int lda,
    const signed char* __restrict__ Bm, int ldb,
    const float* __restrict__ bias,
    void* __restrict__ Cp, int ldc,
    int M, int N, int K,
    const float* __restrict__ resid,
    u32* __restrict__ amaxOut,
    const u32* __restrict__ amaxA, const u32* __restrict__ amaxB) {
  constexpr int BK = 128;
  constexpr int MF = (BM / 2) / 16;
  constexpr int NF = (BN / 2) / 16;
  __shared__ __align__(16) signed char As[2][BM * BK];
  __shared__ __align__(16) signed char Bs[2][BN * BK];
  const int tid = threadIdx.x;
  const int wid = tid >> 6, lane = tid & 63;
  const int wr = wid >> 1, wc = wid & 1;

  float sa = fmaxf(slotMax(amaxA) * (1.0f / 127.0f), 1e-8f);
  float sb = fmaxf(slotMax(amaxB) * (1.0f / 127.0f), 1e-8f);
  const float sAB = sa * sb;

  int bx = blockIdx.x, by = blockIdx.y;
  if (SWZ) {
    int gx = gridDim.x;
    int nwg = gx * gridDim.y;       // all SWZ call sites have nwg % 8 == 0
    int bid = by * gx + bx;
    int cpx = nwg >> 3;
    int swz = (bid & 7) * cpx + (bid >> 3);
    bx = swz % gx;
    by = swz / gx;
  }

  const signed char* Ab = A + (long)by * BM * lda;
  const signed char* Bb = Bm + (long)bx * BN * ldb;

  i32x4 acc[MF][NF];
#pragma unroll
  for (int m = 0; m < MF; m++)
#pragma unroll
    for (int n = 0; n < NF; n++) acc[m][n] = (i32x4){0, 0, 0, 0};

  const int lr = lane & 15;
  const int l8 = lane >> 3;              // row within 8-row stripe
  const int s8 = (lane & 7) ^ l8;        // swizzled 16B slot to fetch
  const long aoff = (long)l8 * lda + s8 * 16;
  const long boff = (long)l8 * ldb + s8 * 16;

  auto stageAB = [&](int buf, int k0) {
#pragma unroll
    for (int i = 0; i < BM / 32; ++i) {
      int R0 = wid * (BM / 4) + i * 8;
      gload16(Ab + (long)R0 * lda + k0 + aoff, &As[buf][R0 * BK]);
    }
#pragma unroll
    for (int i = 0; i < BN / 32; ++i) {
      int R0 = wid * (BN / 4) + i * 8;
      gload16(Bb + (long)R0 * ldb + k0 + boff, &Bs[buf][R0 * BK]);
    }
  };

  auto waitCounted = [&]() {
    if constexpr ((BM / 32 + BN / 32) == 8) {
      asm volatile("s_waitcnt vmcnt(8)" ::: "memory");
    } else {
      asm volatile("s_waitcnt vmcnt(6)" ::: "memory");
    }
  };

  auto computeK = [&](int buf) {
#pragma unroll
    for (int kk = 0; kk < 2; ++kk) {
      const int sl = (kk << 2) + (lane >> 4);       // 16B slot (K=64 chunk)
      const int sf = (sl ^ (lr & 7)) << 4;          // swizzled byte offset
      i32x4 af[MF], bfr[NF];
#pragma unroll
      for (int m = 0; m < MF; m++)
        af[m] = *(const i32x4*)&As[buf][(wr * (BM / 2) + m * 16 + lr) * BK + sf];
#pragma unroll
      for (int n = 0; n < NF; n++)
        bfr[n] = *(const i32x4*)&Bs[buf][(wc * (BN / 2) + n * 16 + lr) * BK + sf];
      __builtin_amdgcn_s_setprio(1);
#pragma unroll
      for (int m = 0; m < MF; m++)
#pragma unroll
        for (int n = 0; n < NF; n++)
          acc[m][n] = __builtin_amdgcn_mfma_i32_16x16x64_i8(af[m], bfr[n], acc[m][n], 0, 0, 0);
      __builtin_amdgcn_s_setprio(0);
    }
  };

  const int nt = K / BK;
  stageAB(0, 0);
  int cur = 0;
  for (int t = 0; t < nt; ++t) {
    if (t + 1 < nt) {
      stageAB(cur ^ 1, (t + 1) * BK);
      waitCounted();
    } else {
      asm volatile("s_waitcnt vmcnt(0)" ::: "memory");
    }
    __builtin_amdgcn_s_barrier();
    computeK(cur);
    if (t + 1 < nt)
      __builtin_amdgcn_s_barrier();
    cur ^= 1;
  }

  const int rowBase = by * BM + wr * (BM / 2);
  const int colBase = bx * BN + wc * (BN / 2);
  float lmax = 0.f;
#pragma unroll
  for (int m = 0; m < MF; m++) {
    int row0 = rowBase + m * 16 + (lane >> 4) * 4;
#pragma unroll
    for (int n = 0; n < NF; n++) {
      int col = colBase + n * 16 + lr;
      float bs = bias[col];
#pragma unroll
      for (int j = 0; j < 4; j++) {
        int row = row0 + j;
        long idx = (long)row * ldc + col;
        float v = (float)acc[m][n][j] * sAB;
        if (EPI == 0) {
          ((u16*)Cp)[idx] = f2bf(v + bs);
        } else if (EPI == 1) {
          ((float*)Cp)[idx] = v + bs + resid[idx];
        } else if (EPI == 2) {
          v += bs;
          float x2 = v * v;
          float e = __expf(v * fmaf(-0.0713548755f, x2, -1.5957691216f));
          v = v * __builtin_amdgcn_rcpf(1.0f + e);
          lmax = fmaxf(fmaxf(lmax, v), 0.0f - v);
          ((u16*)Cp)[idx] = f2bf(v);
        } else if (EPI == 3) {
          ((float*)Cp)[idx] = v + bs + resid[idx];
        }
      }
    }
  }
  if (EPI == 2) {
    __shared__ float redm[4];
    float wm = wredMax(lmax);
    if (lane == 0) redm[wid] = wm;
    __syncthreads();
    if (tid == 0) {
      float bm = fmaxf(fmaxf(redm[0], redm[1]), fmaxf(redm[2], redm[3]));
      slotAtomicMax(amaxOut, blockIdx.y * gridDim.x + blockIdx.x, bm);
    }
  }
}

// ---------------- host ----------------
extern "C" void kernel_launch(void* const* d_in, const int* in_sizes, int n_in,
                              void* d_out, int out_size, void* d_ws, size_t ws_size,
                              hipStream_t stream) {
  const float* hidden = (const float*)d_in[0];
  const float* mask = (const float*)d_in[1];
  const float* ln1g = (const float*)d_in[2];
  const float* ln1b = (const float*)d_in[3];
  const float* ln2g = (const float*)d_in[4];
  const float* ln2b = (const float*)d_in[5];
  const float* w_qkv = (const float*)d_in[6];
  const float* b_qkv = (const float*)d_in[7];
  const float* w_out = (const float*)d_in[8];
  const float* b_out = (const float*)d_in[9];
  const float* w1 = (const float*)d_in[10];
  const float* b1 = (const float*)d_in[11];
  const float* w2 = (const float*)d_in[12];
  const float* b2 = (const float*)d_in[13];

  char* ws = (char*)d_ws;
  // slot arrays: 8 logical maxes x 64 slots x 64B = 32 KB
  // [0]wqkv [1]wout [2]w1 [3]w2 [4]x1 [5]O [6]x2 [7]y1
  u32* sc = (u32*)ws;
  const long MB = 1024 * 1024;
  signed char* wq_qkv = (signed char*)(ws + 1 * MB);    // 3 MB
  signed char* wq_out = (signed char*)(ws + 4 * MB);    // 1 MB
  signed char* wq_w1  = (signed char*)(ws + 6 * MB);    // 4 MB
  signed char* wq_w2  = (signed char*)(ws + 10 * MB);   // 4 MB
  signed char* xq     = (signed char*)(ws + 14 * MB);   // 4 MB (x1q / x2q)
  u16* x1             = (u16*)(ws + 18 * MB);           // 8 MB (LN out bf16)
  signed char* Oq     = (signed char*)(ws + 26 * MB);   // 4 MB
  u16* O              = (u16*)(ws + 30 * MB);           // 8 MB
  u16* qkv            = (u16*)(ws + 38 * MB);           // 24 MB
  float* hbuf         = (float*)(ws + 62 * MB);         // 16 MB
  u16* y1             = (u16*)(ws + 78 * MB);           // 32 MB
  signed char* y1q    = (signed char*)(ws + 110 * MB);  // 16 MB

  k_init<<<32, 256, 0, stream>>>(sc);

  // weight absmax + int8 quant (2 launches)
  k_absmax4<<<512, 256, 0, stream>>>(
      w_qkv, 3 * C_ * C_ / 4, w_out, C_ * C_ / 4, w1, I_ * C_ / 4, w2, C_ * I_ / 4, sc);
  k_quant4<<<512, 256, 0, stream>>>(
      w_qkv, wq_qkv, 3 * C_ * C_ / 4, w_out, wq_out, C_ * C_ / 4,
      w1, wq_w1, I_ * C_ / 4, w2, wq_w2, C_ * I_ / 4, sc);

  // LN1 -> bf16 + amax; quantize to int8
  k_ln<<<BT, 256, 0, stream>>>(hidden, ln1g, ln1b, x1, sc + 4 * 1024);
  k_quant_b8<<<512, 256, 0, stream>>>(x1, xq, BT * C_ / 8, sc + 4 * 1024);

  // qkv = (xq . wq_qkv^T)*s + b -> bf16 [4096,3072]
  k_gemmq<128, 128, 0, true><<<dim3(24, 32), 256, 0, stream>>>(
      xq, C_, wq_qkv, C_, b_qkv, qkv, 3 * C_,
      BT, 3 * C_, C_, nullptr, nullptr, sc + 4 * 1024, sc + 0 * 1024);

  // fused attention -> O bf16 [4096,1024] (b,t,h*64+d), + amax
  k_attn<<<dim3(NH, 2), 256, 0, stream>>>(qkv, mask, O, sc + 5 * 1024);
  k_quant_b8<<<512, 256, 0, stream>>>(O, Oq, BT * C_ / 8, sc + 5 * 1024);

  // h = hidden + (Oq . wq_out^T)*s + b -> f32
  k_gemmq<64, 128, 1, true><<<dim3(8, 64), 256, 0, stream>>>(
      Oq, C_, wq_out, C_, b_out, hbuf, C_,
      BT, C_, C_, hidden, nullptr, sc + 5 * 1024, sc + 1 * 1024);

  // LN2 -> bf16 + amax; quantize
  k_ln<<<BT, 256, 0, stream>>>(hbuf, ln2g, ln2b, x1, sc + 6 * 1024);
  k_quant_b8<<<512, 256, 0, stream>>>(x1, xq, BT * C_ / 8, sc + 6 * 1024);

  // y1 = gelu((xq . wq_w1^T)*s + b1) -> bf16 [4096,4096], + amax
  k_gemmq<128, 128, 2, true><<<dim3(32, 32), 256, 0, stream>>>(
      xq, C_, wq_w1, C_, b1, y1, I_,
      BT, I_, C_, nullptr, sc + 7 * 1024, sc + 6 * 1024, sc + 2 * 1024);
  k_quant_b8<<<512, 256, 0, stream>>>(y1, y1q, BT * I_ / 8, sc + 7 * 1024);

  // out = h + (y1q . wq_w2^T)*s + b2 -> f32 d_out
  k_gemmq<64, 128, 3, true><<<dim3(8, 64), 256, 0, stream>>>(
      y1q, I_, wq_w2, I_, b2, d_out, C_,
      BT, C_, I_, hbuf, nullptr, sc + 7 * 1024, sc + 3 * 1024);
}